// Round 1
// baseline (315.713 us; speedup 1.0000x reference)
//
#include <hip/hip_runtime.h>
#include <hip/hip_bf16.h>
#include <stdint.h>

#define Bdim 2
#define Sdim 2048
#define Ddim 1024
#define Hdim 16
// DK = 64, BH = 32, M = B*S = 4096

typedef unsigned short u16;
typedef __bf16 bf16x8 __attribute__((ext_vector_type(8)));
typedef float f32x4 __attribute__((ext_vector_type(4)));

__device__ __forceinline__ u16 f2b(float x) {
  __hip_bfloat16 h = __float2bfloat16(x);
  return __builtin_bit_cast(u16, h);
}
__device__ __forceinline__ float b2f(u16 u) {
  return __bfloat162float(__builtin_bit_cast(__hip_bfloat16, u));
}
__device__ __forceinline__ f32x4 mfma_bf16(bf16x8 a, bf16x8 b, f32x4 c) {
  return __builtin_amdgcn_mfma_f32_16x16x32_bf16(a, b, c, 0, 0, 0);
}

// ---------------------------------------------------------------------------
// Kernel 1: fp32 -> bf16 conversion of q,k,v (4Mi elems each) and the 4
// weights (1Mi each). 16Mi elems total, 4 per thread.
// ---------------------------------------------------------------------------
__global__ __launch_bounds__(256) void k_convert(
    const float* __restrict__ q, const float* __restrict__ k, const float* __restrict__ v,
    const float* __restrict__ wq, const float* __restrict__ wk,
    const float* __restrict__ wv, const float* __restrict__ wo,
    u16* __restrict__ qb, u16* __restrict__ kb, u16* __restrict__ vb,
    u16* __restrict__ wqb, u16* __restrict__ wkb, u16* __restrict__ wvb, u16* __restrict__ wob) {
  int i = (blockIdx.x * 256 + threadIdx.x) * 4;
  const float* src;
  u16* dst;
  int off;
  if (i < 12582912) {              // 3 * 4Mi
    int s = i >> 22;
    off = i - (s << 22);
    src = (s == 0) ? q : ((s == 1) ? k : v);
    dst = (s == 0) ? qb : ((s == 1) ? kb : vb);
  } else {
    int j = i - 12582912;
    int s = j >> 20;
    off = j - (s << 20);
    src = (s == 0) ? wq : ((s == 1) ? wk : ((s == 2) ? wv : wo));
    dst = (s == 0) ? wqb : ((s == 1) ? wkb : ((s == 2) ? wvb : wob));
  }
  float4 f = *(const float4*)(src + off);
  ushort4 o;
  o.x = f2b(f.x); o.y = f2b(f.y); o.z = f2b(f.z); o.w = f2b(f.w);
  *(ushort4*)(dst + off) = o;
}

// ---------------------------------------------------------------------------
// Kernel 2: RoPE cos/sin table, [S][32] each, fp32.
// inv_freq[j] = 10000^(-j/32) = exp(-j * ln(10000)/32)
// ---------------------------------------------------------------------------
__global__ __launch_bounds__(256) void k_ropetab(float* __restrict__ cosT, float* __restrict__ sinT) {
  int i = blockIdx.x * 256 + threadIdx.x;   // 0 .. 65536
  int s = i >> 5, j = i & 31;
  float invf = expf(-(float)j * 0.28782313662425574f);  // ln(1e4)/32
  float ang = (float)s * invf;
  float sn, cs;
  sincosf(ang, &sn, &cs);
  cosT[i] = cs;
  sinT[i] = sn;
}

// ---------------------------------------------------------------------------
// Kernel 3: GEMM  C[M,N] = A[M,K] @ W[N,K]^T   (M=4096, N=K=1024, bf16 in,
// fp32 accum). 128x128 tile, BK=32, 4 waves (2x2), 4x4 16x16x32 frags/wave.
// OUTF=0 -> bf16 out, OUTF=1 -> fp32 out. blockIdx.z selects operand triple.
// ---------------------------------------------------------------------------
template <int OUTF>
__global__ __launch_bounds__(256) void k_gemm(
    const u16* __restrict__ A0, const u16* __restrict__ W0, void* __restrict__ O0,
    const u16* __restrict__ A1, const u16* __restrict__ W1, void* __restrict__ O1,
    const u16* __restrict__ A2, const u16* __restrict__ W2, void* __restrict__ O2) {
  const u16* A = (blockIdx.z == 0) ? A0 : ((blockIdx.z == 1) ? A1 : A2);
  const u16* W = (blockIdx.z == 0) ? W0 : ((blockIdx.z == 1) ? W1 : W2);
  void* O = (blockIdx.z == 0) ? O0 : ((blockIdx.z == 1) ? O1 : O2);

  __shared__ u16 As[128 * 32];
  __shared__ u16 Bs[128 * 32];

  const int tid = threadIdx.x;
  const int wave = tid >> 6, lane = tid & 63;
  const int g = lane >> 4, cc = lane & 15;
  const int wm = wave >> 1, wn = wave & 1;
  const int row0 = blockIdx.x * 128, col0 = blockIdx.y * 128;

  const u16* Ap = A + (row0 + (tid >> 1)) * 1024 + (tid & 1) * 16;
  const u16* Wp = W + (col0 + (tid >> 1)) * 1024 + (tid & 1) * 16;
  u16* asp = &As[(tid >> 1) * 32 + (tid & 1) * 16];
  u16* bsp = &Bs[(tid >> 1) * 32 + (tid & 1) * 16];

  f32x4 acc[4][4] = {};

  uint4 a0 = *(const uint4*)(Ap);
  uint4 a1 = *(const uint4*)(Ap + 8);
  uint4 b0 = *(const uint4*)(Wp);
  uint4 b1 = *(const uint4*)(Wp + 8);

  for (int k0 = 0; k0 < 1024; k0 += 32) {
    __syncthreads();
    *(uint4*)asp = a0; *(uint4*)(asp + 8) = a1;
    *(uint4*)bsp = b0; *(uint4*)(bsp + 8) = b1;
    __syncthreads();
    if (k0 + 32 < 1024) {
      a0 = *(const uint4*)(Ap + k0 + 32);
      a1 = *(const uint4*)(Ap + k0 + 40);
      b0 = *(const uint4*)(Wp + k0 + 32);
      b1 = *(const uint4*)(Wp + k0 + 40);
    }
    bf16x8 af[4], bfv[4];
#pragma unroll
    for (int mi = 0; mi < 4; ++mi)
      af[mi] = *(const bf16x8*)&As[(wm * 64 + mi * 16 + cc) * 32 + g * 8];
#pragma unroll
    for (int ni = 0; ni < 4; ++ni)
      bfv[ni] = *(const bf16x8*)&Bs[(wn * 64 + ni * 16 + cc) * 32 + g * 8];
#pragma unroll
    for (int mi = 0; mi < 4; ++mi)
#pragma unroll
      for (int ni = 0; ni < 4; ++ni)
        acc[mi][ni] = mfma_bf16(af[mi], bfv[ni], acc[mi][ni]);
  }

#pragma unroll
  for (int mi = 0; mi < 4; ++mi)
#pragma unroll
    for (int ni = 0; ni < 4; ++ni)
#pragma unroll
      for (int r = 0; r < 4; ++r) {
        const int row = row0 + wm * 64 + mi * 16 + g * 4 + r;
        const int col = col0 + wn * 64 + ni * 16 + cc;
        const float vv = acc[mi][ni][r];
        if (OUTF)
          ((float*)O)[row * 1024 + col] = vv;
        else
          ((u16*)O)[row * 1024 + col] = f2b(vv);
      }
}

// ---------------------------------------------------------------------------
// Kernel 4: RoPE + [B,S,H,DK]->[B,H,S,DK] relayout for Q (scaled 1/8) and K.
// Thread = one (tensor, b, s, h, j) with j in [0,32) handling the (j, j+32)
// rotation pair.
// ---------------------------------------------------------------------------
__global__ __launch_bounds__(256) void k_rope(
    const u16* __restrict__ tq, const u16* __restrict__ tk,
    const float* __restrict__ cosT, const float* __restrict__ sinT,
    u16* __restrict__ Qr, u16* __restrict__ Kr) {
  int idx = blockIdx.x * 256 + threadIdx.x;  // 0 .. 4Mi
  int t = idx >> 21;
  int r = idx & ((1 << 21) - 1);
  int j = r & 31;
  int h = (r >> 5) & 15;
  int s = (r >> 9) & 2047;
  int b = (r >> 20) & 1;

  const u16* in = t ? tk : tq;
  u16* out = t ? Kr : Qr;

  int bi = (b * Sdim + s) * Ddim + h * 64 + j;
  float x1 = b2f(in[bi]);
  float x2 = b2f(in[bi + 32]);
  float cv = cosT[s * 32 + j];
  float sv = sinT[s * 32 + j];
  float o1 = x1 * cv - x2 * sv;
  float o2 = x2 * cv + x1 * sv;
  if (t == 0) { o1 *= 0.125f; o2 *= 0.125f; }  // 1/sqrt(DK) folded into Q
  int bo = ((b * Hdim + h) * Sdim + s) * 64 + j;
  out[bo] = f2b(o1);
  out[bo + 32] = f2b(o2);
}

// ---------------------------------------------------------------------------
// Kernel 5: V relayout+transpose: tmpV [B,S,H*DK] -> Vt [B*H, DK, S]
// 64x64 tiles through LDS.
// ---------------------------------------------------------------------------
__global__ __launch_bounds__(256) void k_transv(const u16* __restrict__ tv, u16* __restrict__ Vt) {
  __shared__ u16 tl[64][72];
  const int bh = blockIdx.y;
  const int b = bh >> 4, h = bh & 15;
  const int s0 = blockIdx.x * 64;
  const int tid = threadIdx.x;
#pragma unroll
  for (int p = 0; p < 4; ++p) {
    int row = p * 16 + (tid >> 4);
    int dc = (tid & 15) * 4;
    ushort4 val = *(const ushort4*)(tv + (b * Sdim + s0 + row) * Ddim + h * 64 + dc);
    *(ushort4*)&tl[row][dc] = val;
  }
  __syncthreads();
#pragma unroll
  for (int p = 0; p < 4; ++p) {
    int dr = p * 16 + (tid >> 4);
    int sc = (tid & 15) * 4;
    ushort4 o;
    o.x = tl[sc + 0][dr];
    o.y = tl[sc + 1][dr];
    o.z = tl[sc + 2][dr];
    o.w = tl[sc + 3][dr];
    *(ushort4*)(Vt + (bh * 64 + dr) * Sdim + s0 + sc) = o;
  }
}

// ---------------------------------------------------------------------------
// Kernel 6: causal flash attention. One wave per 16-row Q tile, 32-key
// chunks, online softmax. Q pre-scaled by 1/8 and roped; K roped; V stored
// transposed [BH, DK, S]. PV computed as O^T = V^T @ P^T so both operands
// are contiguous b128 fragment reads. Output written to Oc [B,S,D] bf16.
// ---------------------------------------------------------------------------
__global__ __launch_bounds__(256) void k_attn(
    const u16* __restrict__ Qr, const u16* __restrict__ Kr,
    const u16* __restrict__ Vt, u16* __restrict__ Oc) {
  __shared__ u16 Pl[4][16][32];
  __shared__ float bl[4][16];
  __shared__ u16 ost[4][16][72];

  const int bh = blockIdx.y;
  const int b = bh >> 4, h = bh & 15;
  const int w = threadIdx.x >> 6;
  const int lane = threadIdx.x & 63;
  const int g = lane >> 4, cc = lane & 15;
  const int qrow0 = (blockIdx.x * 4 + w) * 16;

  const u16* Qp = Qr + (bh * Sdim + qrow0) * 64;
  const u16* Kp = Kr + bh * Sdim * 64;
  const u16* Vp = Vt + bh * 64 * Sdim;

  bf16x8 qf0 = *(const bf16x8*)(Qp + cc * 64 + g * 8);
  bf16x8 qf1 = *(const bf16x8*)(Qp + cc * 64 + g * 8 + 32);

  float mold[4] = {-1e30f, -1e30f, -1e30f, -1e30f};
  float lsum[4] = {0.f, 0.f, 0.f, 0.f};
  float moldT = -1e30f;
  f32x4 ot[4] = {};

  const int nch = ((qrow0 + 15) >> 5) + 1;
  for (int kb = 0; kb < nch; ++kb) {
    const int j0 = kb * 32;
    const u16* kp = Kp + (j0 + cc) * 64 + g * 8;
    bf16x8 k00 = *(const bf16x8*)(kp);
    bf16x8 k01 = *(const bf16x8*)(kp + 32);
    bf16x8 k10 = *(const bf16x8*)(kp + 16 * 64);
    bf16x8 k11 = *(const bf16x8*)(kp + 16 * 64 + 32);

    f32x4 sA = {}, sB = {};
    sA = mfma_bf16(qf0, k00, sA);
    sA = mfma_bf16(qf1, k01, sA);
    sB = mfma_bf16(qf0, k10, sB);
    sB = mfma_bf16(qf1, k11, sB);

    float mr[4], pA[4], pB[4];
#pragma unroll
    for (int r = 0; r < 4; ++r) {
      const int irow = qrow0 + g * 4 + r;
      float a = (j0 + cc <= irow) ? sA[r] : -1000.0f;
      float bb = (j0 + 16 + cc <= irow) ? sB[r] : -1000.0f;
      sA[r] = a;
      sB[r] = bb;
      float m = fmaxf(a, bb);
      m = fmaxf(m, __shfl_xor(m, 1));
      m = fmaxf(m, __shfl_xor(m, 2));
      m = fmaxf(m, __shfl_xor(m, 4));
      m = fmaxf(m, __shfl_xor(m, 8));
      mr[r] = m;
    }
    if (cc == 0) {
#pragma unroll
      for (int r = 0; r < 4; ++r) bl[w][g * 4 + r] = mr[r];
    }
#pragma unroll
    for (int r = 0; r < 4; ++r) {
      const float mnew = fmaxf(mold[r], mr[r]);
      const float al = __expf(mold[r] - mnew);
      pA[r] = __expf(sA[r] - mnew);
      pB[r] = __expf(sB[r] - mnew);
      float rs = pA[r] + pB[r];
      rs += __shfl_xor(rs, 1);
      rs += __shfl_xor(rs, 2);
      rs += __shfl_xor(rs, 4);
      rs += __shfl_xor(rs, 8);
      lsum[r] = lsum[r] * al + rs;
      mold[r] = mnew;
    }
#pragma unroll
    for (int r = 0; r < 4; ++r) {
      Pl[w][g * 4 + r][cc] = f2b(pA[r]);
      Pl[w][g * 4 + r][cc + 16] = f2b(pB[r]);
    }
    asm volatile("s_waitcnt lgkmcnt(0)" ::: "memory");
    __builtin_amdgcn_sched_barrier(0);

    const float mrT = bl[w][cc];
    const float mnT = fmaxf(moldT, mrT);
    const float alT = __expf(moldT - mnT);
    moldT = mnT;

    bf16x8 pb = *(const bf16x8*)&Pl[w][cc][g * 8];
#pragma unroll
    for (int dc = 0; dc < 4; ++dc) {
      ot[dc] *= alT;
      bf16x8 va = *(const bf16x8*)(Vp + (dc * 16 + cc) * Sdim + j0 + g * 8);
      ot[dc] = mfma_bf16(va, pb, ot[dc]);
    }
  }

  if (cc == 0) {
#pragma unroll
    for (int r = 0; r < 4; ++r) bl[w][g * 4 + r] = lsum[r];
  }
  asm volatile("s_waitcnt lgkmcnt(0)" ::: "memory");
  __builtin_amdgcn_sched_barrier(0);
  const float rl = 1.0f / bl[w][cc];
#pragma unroll
  for (int dc = 0; dc < 4; ++dc)
#pragma unroll
    for (int r = 0; r < 4; ++r)
      ost[w][cc][dc * 16 + g * 4 + r] = f2b(ot[dc][r] * rl);
  asm volatile("s_waitcnt lgkmcnt(0)" ::: "memory");
  __builtin_amdgcn_sched_barrier(0);

  const int i = lane >> 2, d0 = (lane & 3) * 16;
  uint4 v0 = *(const uint4*)&ost[w][i][d0];
  uint4 v1 = *(const uint4*)&ost[w][i][d0 + 8];
  u16* dst = Oc + (b * Sdim + qrow0 + i) * Ddim + h * 64 + d0;
  *(uint4*)dst = v0;
  *(uint4*)(dst + 8) = v1;
}

// ---------------------------------------------------------------------------
extern "C" void kernel_launch(void* const* d_in, const int* in_sizes, int n_in,
                              void* d_out, int out_size, void* d_ws, size_t ws_size,
                              hipStream_t stream) {
  const float* q = (const float*)d_in[0];
  const float* k = (const float*)d_in[1];
  const float* v = (const float*)d_in[2];
  const float* wq = (const float*)d_in[3];
  const float* wk = (const float*)d_in[4];
  const float* wv = (const float*)d_in[5];
  const float* wo = (const float*)d_in[6];
  float* out = (float*)d_out;

  uint8_t* ws = (uint8_t*)d_ws;
  const size_t MiB = 1ull << 20;
  u16* qb  = (u16*)(ws + 0 * MiB);
  u16* kb  = (u16*)(ws + 8 * MiB);
  u16* vb  = (u16*)(ws + 16 * MiB);
  u16* wqb = (u16*)(ws + 24 * MiB);
  u16* wkb = (u16*)(ws + 26 * MiB);
  u16* wvb = (u16*)(ws + 28 * MiB);
  u16* wob = (u16*)(ws + 30 * MiB);
  u16* tQ  = (u16*)(ws + 32 * MiB);
  u16* tK  = (u16*)(ws + 40 * MiB);
  u16* tV  = (u16*)(ws + 48 * MiB);
  u16* Qr  = (u16*)(ws + 56 * MiB);
  u16* Kr  = (u16*)(ws + 64 * MiB);
  u16* Vt  = (u16*)(ws + 72 * MiB);
  u16* Oc  = (u16*)(ws + 80 * MiB);
  float* cosT = (float*)(ws + 88 * MiB);
  float* sinT = (float*)(ws + 88 * MiB + 256 * 1024);

  k_convert<<<16384, 256, 0, stream>>>(q, k, v, wq, wk, wv, wo,
                                       qb, kb, vb, wqb, wkb, wvb, wob);
  k_ropetab<<<256, 256, 0, stream>>>(cosT, sinT);
  k_gemm<0><<<dim3(32, 8, 3), 256, 0, stream>>>(qb, wqb, tQ, kb, wkb, tK, vb, wvb, tV);
  k_rope<<<16384, 256, 0, stream>>>(tQ, tK, cosT, sinT, Qr, Kr);
  k_transv<<<dim3(32, 32), 256, 0, stream>>>(tV, Vt);
  k_attn<<<dim3(32, 32), 256, 0, stream>>>(Qr, Kr, Vt, Oc);
  k_gemm<1><<<dim3(32, 8, 1), 256, 0, stream>>>(Oc, wob, out, Oc, wob, out, Oc, wob, out);
}

// Round 2
// 262.871 us; speedup vs baseline: 1.2010x; 1.2010x over previous
//
#include <hip/hip_runtime.h>
#include <hip/hip_bf16.h>
#include <stdint.h>

#define Bdim 2
#define Sdim 2048
#define Ddim 1024
#define Hdim 16
// DK = 64, BH = 32, M = B*S = 4096

typedef unsigned short u16;
typedef __bf16 bf16x8 __attribute__((ext_vector_type(8)));
typedef float f32x4 __attribute__((ext_vector_type(4)));

__device__ __forceinline__ u16 f2b(float x) {
  __hip_bfloat16 h = __float2bfloat16(x);
  return __builtin_bit_cast(u16, h);
}
__device__ __forceinline__ float b2f(u16 u) {
  return __bfloat162float(__builtin_bit_cast(__hip_bfloat16, u));
}
__device__ __forceinline__ f32x4 mfma_bf16(bf16x8 a, bf16x8 b, f32x4 c) {
  return __builtin_amdgcn_mfma_f32_16x16x32_bf16(a, b, c, 0, 0, 0);
}

// ---------------------------------------------------------------------------
// Kernel 1: fp32 -> bf16 conversion of q,k,v (4Mi elems each) and the 4
// weights (1Mi each). 16Mi elems total, 4 per thread.
// ---------------------------------------------------------------------------
__global__ __launch_bounds__(256) void k_convert(
    const float* __restrict__ q, const float* __restrict__ k, const float* __restrict__ v,
    const float* __restrict__ wq, const float* __restrict__ wk,
    const float* __restrict__ wv, const float* __restrict__ wo,
    u16* __restrict__ qb, u16* __restrict__ kb, u16* __restrict__ vb,
    u16* __restrict__ wqb, u16* __restrict__ wkb, u16* __restrict__ wvb, u16* __restrict__ wob) {
  int i = (blockIdx.x * 256 + threadIdx.x) * 4;
  const float* src;
  u16* dst;
  int off;
  if (i < 12582912) {              // 3 * 4Mi
    int s = i >> 22;
    off = i - (s << 22);
    src = (s == 0) ? q : ((s == 1) ? k : v);
    dst = (s == 0) ? qb : ((s == 1) ? kb : vb);
  } else {
    int j = i - 12582912;
    int s = j >> 20;
    off = j - (s << 20);
    src = (s == 0) ? wq : ((s == 1) ? wk : ((s == 2) ? wv : wo));
    dst = (s == 0) ? wqb : ((s == 1) ? wkb : ((s == 2) ? wvb : wob));
  }
  float4 f = *(const float4*)(src + off);
  ushort4 o;
  o.x = f2b(f.x); o.y = f2b(f.y); o.z = f2b(f.z); o.w = f2b(f.w);
  *(ushort4*)(dst + off) = o;
}

// ---------------------------------------------------------------------------
// Kernel 2: RoPE cos/sin table, [S][32] each, fp32.
// ---------------------------------------------------------------------------
__global__ __launch_bounds__(256) void k_ropetab(float* __restrict__ cosT, float* __restrict__ sinT) {
  int i = blockIdx.x * 256 + threadIdx.x;   // 0 .. 65536
  int s = i >> 5, j = i & 31;
  float invf = expf(-(float)j * 0.28782313662425574f);  // ln(1e4)/32
  float ang = (float)s * invf;
  float sn, cs;
  sincosf(ang, &sn, &cs);
  cosT[i] = cs;
  sinT[i] = sn;
}

// ---------------------------------------------------------------------------
// Kernel 3: GEMM  C[M,N] = A[M,K] @ W[N,K]^T   (M=4096, N=K=1024, bf16 in,
// fp32 accum). 128x128 tile, BK=32, 4 waves (2x2), 4x4 16x16x32 frags/wave.
// ---------------------------------------------------------------------------
template <int OUTF>
__global__ __launch_bounds__(256) void k_gemm(
    const u16* __restrict__ A0, const u16* __restrict__ W0, void* __restrict__ O0,
    const u16* __restrict__ A1, const u16* __restrict__ W1, void* __restrict__ O1,
    const u16* __restrict__ A2, const u16* __restrict__ W2, void* __restrict__ O2) {
  const u16* A = (blockIdx.z == 0) ? A0 : ((blockIdx.z == 1) ? A1 : A2);
  const u16* W = (blockIdx.z == 0) ? W0 : ((blockIdx.z == 1) ? W1 : W2);
  void* O = (blockIdx.z == 0) ? O0 : ((blockIdx.z == 1) ? O1 : O2);

  __shared__ u16 As[128 * 32];
  __shared__ u16 Bs[128 * 32];

  const int tid = threadIdx.x;
  const int wave = tid >> 6, lane = tid & 63;
  const int g = lane >> 4, cc = lane & 15;
  const int wm = wave >> 1, wn = wave & 1;
  const int row0 = blockIdx.x * 128, col0 = blockIdx.y * 128;

  const u16* Ap = A + (row0 + (tid >> 1)) * 1024 + (tid & 1) * 16;
  const u16* Wp = W + (col0 + (tid >> 1)) * 1024 + (tid & 1) * 16;
  u16* asp = &As[(tid >> 1) * 32 + (tid & 1) * 16];
  u16* bsp = &Bs[(tid >> 1) * 32 + (tid & 1) * 16];

  f32x4 acc[4][4] = {};

  uint4 a0 = *(const uint4*)(Ap);
  uint4 a1 = *(const uint4*)(Ap + 8);
  uint4 b0 = *(const uint4*)(Wp);
  uint4 b1 = *(const uint4*)(Wp + 8);

  for (int k0 = 0; k0 < 1024; k0 += 32) {
    __syncthreads();
    *(uint4*)asp = a0; *(uint4*)(asp + 8) = a1;
    *(uint4*)bsp = b0; *(uint4*)(bsp + 8) = b1;
    __syncthreads();
    if (k0 + 32 < 1024) {
      a0 = *(const uint4*)(Ap + k0 + 32);
      a1 = *(const uint4*)(Ap + k0 + 40);
      b0 = *(const uint4*)(Wp + k0 + 32);
      b1 = *(const uint4*)(Wp + k0 + 40);
    }
    bf16x8 af[4], bfv[4];
#pragma unroll
    for (int mi = 0; mi < 4; ++mi)
      af[mi] = *(const bf16x8*)&As[(wm * 64 + mi * 16 + cc) * 32 + g * 8];
#pragma unroll
    for (int ni = 0; ni < 4; ++ni)
      bfv[ni] = *(const bf16x8*)&Bs[(wn * 64 + ni * 16 + cc) * 32 + g * 8];
#pragma unroll
    for (int mi = 0; mi < 4; ++mi)
#pragma unroll
      for (int ni = 0; ni < 4; ++ni)
        acc[mi][ni] = mfma_bf16(af[mi], bfv[ni], acc[mi][ni]);
  }

#pragma unroll
  for (int mi = 0; mi < 4; ++mi)
#pragma unroll
    for (int ni = 0; ni < 4; ++ni)
#pragma unroll
      for (int r = 0; r < 4; ++r) {
        const int row = row0 + wm * 64 + mi * 16 + g * 4 + r;
        const int col = col0 + wn * 64 + ni * 16 + cc;
        const float vv = acc[mi][ni][r];
        if (OUTF)
          ((float*)O)[row * 1024 + col] = vv;
        else
          ((u16*)O)[row * 1024 + col] = f2b(vv);
      }
}

// ---------------------------------------------------------------------------
// Kernel 4: RoPE + [B,S,H,DK]->[B,H,S,DK] relayout for Q (scaled 1/8) and K.
// ---------------------------------------------------------------------------
__global__ __launch_bounds__(256) void k_rope(
    const u16* __restrict__ tq, const u16* __restrict__ tk,
    const float* __restrict__ cosT, const float* __restrict__ sinT,
    u16* __restrict__ Qr, u16* __restrict__ Kr) {
  int idx = blockIdx.x * 256 + threadIdx.x;  // 0 .. 4Mi
  int t = idx >> 21;
  int r = idx & ((1 << 21) - 1);
  int j = r & 31;
  int h = (r >> 5) & 15;
  int s = (r >> 9) & 2047;
  int b = (r >> 20) & 1;

  const u16* in = t ? tk : tq;
  u16* out = t ? Kr : Qr;

  int bi = (b * Sdim + s) * Ddim + h * 64 + j;
  float x1 = b2f(in[bi]);
  float x2 = b2f(in[bi + 32]);
  float cv = cosT[s * 32 + j];
  float sv = sinT[s * 32 + j];
  float o1 = x1 * cv - x2 * sv;
  float o2 = x2 * cv + x1 * sv;
  if (t == 0) { o1 *= 0.125f; o2 *= 0.125f; }  // 1/sqrt(DK) folded into Q
  int bo = ((b * Hdim + h) * Sdim + s) * 64 + j;
  out[bo] = f2b(o1);
  out[bo + 32] = f2b(o2);
}

// ---------------------------------------------------------------------------
// Kernel 5: V relayout+transpose: tmpV [B,S,H*DK] -> Vt [B*H, DK, S]
// ---------------------------------------------------------------------------
__global__ __launch_bounds__(256) void k_transv(const u16* __restrict__ tv, u16* __restrict__ Vt) {
  __shared__ u16 tl[64][72];
  const int bh = blockIdx.y;
  const int b = bh >> 4, h = bh & 15;
  const int s0 = blockIdx.x * 64;
  const int tid = threadIdx.x;
#pragma unroll
  for (int p = 0; p < 4; ++p) {
    int row = p * 16 + (tid >> 4);
    int dc = (tid & 15) * 4;
    ushort4 val = *(const ushort4*)(tv + (b * Sdim + s0 + row) * Ddim + h * 64 + dc);
    *(ushort4*)&tl[row][dc] = val;
  }
  __syncthreads();
#pragma unroll
  for (int p = 0; p < 4; ++p) {
    int dr = p * 16 + (tid >> 4);
    int sc = (tid & 15) * 4;
    ushort4 o;
    o.x = tl[sc + 0][dr];
    o.y = tl[sc + 1][dr];
    o.z = tl[sc + 2][dr];
    o.w = tl[sc + 3][dr];
    *(ushort4*)(Vt + (bh * 64 + dr) * Sdim + s0 + sc) = o;
  }
}

// ---------------------------------------------------------------------------
// Kernel 6: causal flash attention, swapped-operand form.
// S^T = mfma(K, Q): lane (g=lane>>4, cc=lane&15) holds 8 scores of q-row
// (qrow0+cc), keys {j0+g*4+r, j0+16+g*4+r}. Softmax is 7 in-reg fmax + 2
// shfl_xor (across g); row-sum reduction deferred to epilogue (linearity).
// P stays in registers and feeds PV's B operand with key-permutation
// kappa(g,j) = g*4+j (j<4) / 16+g*4+(j-4); V^T (A operand) is loaded with
// the SAME kappa, so the fixed hardware (g,reg)->k pairing cancels.
// O^T accumulated per-lane; Q pre-scaled 1/8+roped, K roped, V transposed.
// Load balance: wave w of block x handles tile pair (p, 127-p), p=x*4+w:
// every wave processes exactly ~129*16 keys.
// ---------------------------------------------------------------------------
template <bool MASKED>
__device__ __forceinline__ void attn_chunk(
    int j0, int qrow0, int cc, int g,
    const u16* __restrict__ Kp, const u16* __restrict__ Vp,
    bf16x8 qf0, bf16x8 qf1,
    float& mold, float& lsum, f32x4 ot[4]) {
  const u16* kp = Kp + (j0 + cc) * 64 + g * 8;
  bf16x8 k00 = *(const bf16x8*)(kp);
  bf16x8 k01 = *(const bf16x8*)(kp + 32);
  bf16x8 k10 = *(const bf16x8*)(kp + 16 * 64);
  bf16x8 k11 = *(const bf16x8*)(kp + 16 * 64 + 32);
  f32x4 sA = {}, sB = {};
  sA = mfma_bf16(k00, qf0, sA);
  sA = mfma_bf16(k01, qf1, sA);
  sB = mfma_bf16(k10, qf0, sB);
  sB = mfma_bf16(k11, qf1, sB);

  const int qglob = qrow0 + cc;
  float p[8];
#pragma unroll
  for (int r = 0; r < 4; ++r) {
    float a = sA[r], bb = sB[r];
    if (MASKED) {
      a = (j0 + g * 4 + r <= qglob) ? a : -1000.0f;
      bb = (j0 + 16 + g * 4 + r <= qglob) ? bb : -1000.0f;
    }
    p[r] = a;
    p[r + 4] = bb;
  }
  float m8 = fmaxf(fmaxf(fmaxf(p[0], p[1]), fmaxf(p[2], p[3])),
                   fmaxf(fmaxf(p[4], p[5]), fmaxf(p[6], p[7])));
  m8 = fmaxf(m8, __shfl_xor(m8, 16));
  m8 = fmaxf(m8, __shfl_xor(m8, 32));
  const float mnew = fmaxf(mold, m8);
  const float alpha = __expf(mold - mnew);
  mold = mnew;

  float rs = 0.f;
  union { bf16x8 v; u16 s[8]; } pu;
#pragma unroll
  for (int j = 0; j < 8; ++j) {
    float e = __expf(p[j] - mnew);
    rs += e;
    pu.s[j] = f2b(e);
  }
  lsum = lsum * alpha + rs;   // per-lane partial (own 8 keys); reduced at end

#pragma unroll
  for (int dc = 0; dc < 4; ++dc) {
    const u16* vp = Vp + (dc * 16 + cc) * Sdim + j0 + g * 4;
    union { bf16x8 v; uint2 h[2]; } vu;
    vu.h[0] = *(const uint2*)(vp);
    vu.h[1] = *(const uint2*)(vp + 16);
    ot[dc] *= alpha;
    ot[dc] = mfma_bf16(vu.v, pu.v, ot[dc]);
  }
}

__global__ __launch_bounds__(256) void k_attn(
    const u16* __restrict__ Qr, const u16* __restrict__ Kr,
    const u16* __restrict__ Vt, u16* __restrict__ Oc) {
  const int bh = blockIdx.y;
  const int b = bh >> 4, h = bh & 15;
  const int w = threadIdx.x >> 6;
  const int lane = threadIdx.x & 63;
  const int g = lane >> 4, cc = lane & 15;
  const int p = blockIdx.x * 4 + w;   // 0..63 pair index

  const u16* Kp = Kr + bh * Sdim * 64;
  const u16* Vp = Vt + bh * 64 * Sdim;

#pragma unroll
  for (int ti = 0; ti < 2; ++ti) {
    const int t = ti ? (127 - p) : p;
    const int qrow0 = t * 16;
    const u16* Qp = Qr + (bh * Sdim + qrow0) * 64;
    bf16x8 qf0 = *(const bf16x8*)(Qp + cc * 64 + g * 8);
    bf16x8 qf1 = *(const bf16x8*)(Qp + cc * 64 + g * 8 + 32);

    float mold = -1e30f, lsum = 0.f;
    f32x4 ot[4] = {};

    const int nfull = (qrow0 + 1) >> 5;   // chunks with j0+31 <= qrow0
    const int nch = (qrow0 + 47) >> 5;    // total chunks (covers qrow0+15)
    int kb = 0;
#pragma unroll 2
    for (; kb < nfull; ++kb)
      attn_chunk<false>(kb * 32, qrow0, cc, g, Kp, Vp, qf0, qf1, mold, lsum, ot);
    for (; kb < nch; ++kb)
      attn_chunk<true>(kb * 32, qrow0, cc, g, Kp, Vp, qf0, qf1, mold, lsum, ot);

    lsum += __shfl_xor(lsum, 16);
    lsum += __shfl_xor(lsum, 32);
    const float rl = 1.0f / lsum;

    u16* dst = Oc + (size_t)(b * Sdim + qrow0 + cc) * Ddim + h * 64 + g * 4;
#pragma unroll
    for (int dc = 0; dc < 4; ++dc) {
      ushort4 o;
      o.x = f2b(ot[dc][0] * rl);
      o.y = f2b(ot[dc][1] * rl);
      o.z = f2b(ot[dc][2] * rl);
      o.w = f2b(ot[dc][3] * rl);
      *(ushort4*)(dst + dc * 16) = o;
    }
  }
}

// ---------------------------------------------------------------------------
extern "C" void kernel_launch(void* const* d_in, const int* in_sizes, int n_in,
                              void* d_out, int out_size, void* d_ws, size_t ws_size,
                              hipStream_t stream) {
  const float* q = (const float*)d_in[0];
  const float* k = (const float*)d_in[1];
  const float* v = (const float*)d_in[2];
  const float* wq = (const float*)d_in[3];
  const float* wk = (const float*)d_in[4];
  const float* wv = (const float*)d_in[5];
  const float* wo = (const float*)d_in[6];
  float* out = (float*)d_out;

  uint8_t* ws = (uint8_t*)d_ws;
  const size_t MiB = 1ull << 20;
  u16* qb  = (u16*)(ws + 0 * MiB);
  u16* kb  = (u16*)(ws + 8 * MiB);
  u16* vb  = (u16*)(ws + 16 * MiB);
  u16* wqb = (u16*)(ws + 24 * MiB);
  u16* wkb = (u16*)(ws + 26 * MiB);
  u16* wvb = (u16*)(ws + 28 * MiB);
  u16* wob = (u16*)(ws + 30 * MiB);
  u16* tQ  = (u16*)(ws + 32 * MiB);
  u16* tK  = (u16*)(ws + 40 * MiB);
  u16* tV  = (u16*)(ws + 48 * MiB);
  u16* Qr  = (u16*)(ws + 56 * MiB);
  u16* Kr  = (u16*)(ws + 64 * MiB);
  u16* Vt  = (u16*)(ws + 72 * MiB);
  u16* Oc  = (u16*)(ws + 80 * MiB);
  float* cosT = (float*)(ws + 88 * MiB);
  float* sinT = (float*)(ws + 88 * MiB + 256 * 1024);

  k_convert<<<16384, 256, 0, stream>>>(q, k, v, wq, wk, wv, wo,
                                       qb, kb, vb, wqb, wkb, wvb, wob);
  k_ropetab<<<256, 256, 0, stream>>>(cosT, sinT);
  k_gemm<0><<<dim3(32, 8, 3), 256, 0, stream>>>(qb, wqb, tQ, kb, wkb, tK, vb, wvb, tV);
  k_rope<<<16384, 256, 0, stream>>>(tQ, tK, cosT, sinT, Qr, Kr);
  k_transv<<<dim3(32, 32), 256, 0, stream>>>(tV, Vt);
  k_attn<<<dim3(16, 32), 256, 0, stream>>>(Qr, Kr, Vt, Oc);
  k_gemm<1><<<dim3(32, 8, 1), 256, 0, stream>>>(Oc, wob, out, Oc, wob, out, Oc, wob, out);
}

// Round 3
// 166.040 us; speedup vs baseline: 1.9014x; 1.5832x over previous
//
#include <hip/hip_runtime.h>
#include <hip/hip_bf16.h>
#include <stdint.h>

#define Bdim 2
#define Sdim 2048
#define Ddim 1024
#define Hdim 16
// DK = 64, BH = 32, M = B*S = 4096

typedef unsigned short u16;
typedef __bf16 bf16x8 __attribute__((ext_vector_type(8)));
typedef float f32x4 __attribute__((ext_vector_type(4)));

__device__ __forceinline__ u16 f2b(float x) {
  __hip_bfloat16 h = __float2bfloat16(x);
  return __builtin_bit_cast(u16, h);
}
__device__ __forceinline__ float b2f(u16 u) {
  return __bfloat162float(__builtin_bit_cast(__hip_bfloat16, u));
}
__device__ __forceinline__ f32x4 mfma_bf16(bf16x8 a, bf16x8 b, f32x4 c) {
  return __builtin_amdgcn_mfma_f32_16x16x32_bf16(a, b, c, 0, 0, 0);
}
__device__ __forceinline__ void gload_lds16(const u16* gp, u16* lp) {
  __builtin_amdgcn_global_load_lds(
      (const __attribute__((address_space(1))) void*)gp,
      (__attribute__((address_space(3))) void*)lp, 16, 0, 0);
}

// ---------------------------------------------------------------------------
// Kernel 1: fp32 -> bf16 conversion of q,k,v and the 4 weights.
// ---------------------------------------------------------------------------
__global__ __launch_bounds__(256) void k_convert(
    const float* __restrict__ q, const float* __restrict__ k, const float* __restrict__ v,
    const float* __restrict__ wq, const float* __restrict__ wk,
    const float* __restrict__ wv, const float* __restrict__ wo,
    u16* __restrict__ qb, u16* __restrict__ kb, u16* __restrict__ vb,
    u16* __restrict__ wqb, u16* __restrict__ wkb, u16* __restrict__ wvb, u16* __restrict__ wob) {
  int i = (blockIdx.x * 256 + threadIdx.x) * 4;
  const float* src;
  u16* dst;
  int off;
  if (i < 12582912) {              // 3 * 4Mi
    int s = i >> 22;
    off = i - (s << 22);
    src = (s == 0) ? q : ((s == 1) ? k : v);
    dst = (s == 0) ? qb : ((s == 1) ? kb : vb);
  } else {
    int j = i - 12582912;
    int s = j >> 20;
    off = j - (s << 20);
    src = (s == 0) ? wq : ((s == 1) ? wk : ((s == 2) ? wv : wo));
    dst = (s == 0) ? wqb : ((s == 1) ? wkb : ((s == 2) ? wvb : wob));
  }
  float4 f = *(const float4*)(src + off);
  ushort4 o;
  o.x = f2b(f.x); o.y = f2b(f.y); o.z = f2b(f.z); o.w = f2b(f.w);
  *(ushort4*)(dst + off) = o;
}

// ---------------------------------------------------------------------------
// Kernel 2: RoPE cos/sin table, [S][32] each, fp32.
// ---------------------------------------------------------------------------
__global__ __launch_bounds__(256) void k_ropetab(float* __restrict__ cosT, float* __restrict__ sinT) {
  int i = blockIdx.x * 256 + threadIdx.x;   // 0 .. 65536
  int s = i >> 5, j = i & 31;
  float invf = expf(-(float)j * 0.28782313662425574f);  // ln(1e4)/32
  float ang = (float)s * invf;
  float sn, cs;
  sincosf(ang, &sn, &cs);
  cosT[i] = cs;
  sinT[i] = sn;
}

// ---------------------------------------------------------------------------
// Kernel 3: GEMM  C[M,N] = A[M,K] @ W[N,K]^T  (bf16 in, fp32 accum).
// 128x128 tile, BK=32, 4 waves. Staging via global_load_lds width=16:
// wave w instr covers LDS rows 16w..16w+15 (linear, lane*16B), so lane l
// sources row row0+16w+(l>>2), 16B seg (l&3). Fragment reads unchanged.
// ---------------------------------------------------------------------------
template <int OUTF>
__global__ __launch_bounds__(256) void k_gemm(
    const u16* __restrict__ A0, const u16* __restrict__ W0, void* __restrict__ O0,
    const u16* __restrict__ A1, const u16* __restrict__ W1, void* __restrict__ O1,
    const u16* __restrict__ A2, const u16* __restrict__ W2, void* __restrict__ O2) {
  const u16* A = (blockIdx.z == 0) ? A0 : ((blockIdx.z == 1) ? A1 : A2);
  const u16* W = (blockIdx.z == 0) ? W0 : ((blockIdx.z == 1) ? W1 : W2);
  void* O = (blockIdx.z == 0) ? O0 : ((blockIdx.z == 1) ? O1 : O2);

  __shared__ u16 As[128 * 32];
  __shared__ u16 Bs[128 * 32];

  const int tid = threadIdx.x;
  const int wave = tid >> 6, lane = tid & 63;
  const int g = lane >> 4, cc = lane & 15;
  const int wm = wave >> 1, wn = wave & 1;
  const int row0 = blockIdx.x * 128, col0 = blockIdx.y * 128;

  const int srow = wave * 16 + (lane >> 2);
  const int sseg = (lane & 3) * 8;
  const u16* Ap  = A + (size_t)(row0 + srow) * 1024 + sseg;
  const u16* Ap2 = Ap + 64 * 1024;
  const u16* Wp  = W + (size_t)(col0 + srow) * 1024 + sseg;
  const u16* Wp2 = Wp + 64 * 1024;
  u16* asl  = &As[wave * 512];
  u16* asl2 = &As[2048 + wave * 512];
  u16* bsl  = &Bs[wave * 512];
  u16* bsl2 = &Bs[2048 + wave * 512];

  f32x4 acc[4][4] = {};

  for (int k0 = 0; k0 < 1024; k0 += 32) {
    __syncthreads();
    gload_lds16(Ap + k0, asl);
    gload_lds16(Ap2 + k0, asl2);
    gload_lds16(Wp + k0, bsl);
    gload_lds16(Wp2 + k0, bsl2);
    __syncthreads();
    bf16x8 af[4], bfv[4];
#pragma unroll
    for (int mi = 0; mi < 4; ++mi)
      af[mi] = *(const bf16x8*)&As[(wm * 64 + mi * 16 + cc) * 32 + g * 8];
#pragma unroll
    for (int ni = 0; ni < 4; ++ni)
      bfv[ni] = *(const bf16x8*)&Bs[(wn * 64 + ni * 16 + cc) * 32 + g * 8];
#pragma unroll
    for (int mi = 0; mi < 4; ++mi)
#pragma unroll
      for (int ni = 0; ni < 4; ++ni)
        acc[mi][ni] = mfma_bf16(af[mi], bfv[ni], acc[mi][ni]);
  }

#pragma unroll
  for (int mi = 0; mi < 4; ++mi)
#pragma unroll
    for (int ni = 0; ni < 4; ++ni)
#pragma unroll
      for (int r = 0; r < 4; ++r) {
        const int row = row0 + wm * 64 + mi * 16 + g * 4 + r;
        const int col = col0 + wn * 64 + ni * 16 + cc;
        const float vv = acc[mi][ni][r];
        if (OUTF)
          ((float*)O)[row * 1024 + col] = vv;
        else
          ((u16*)O)[row * 1024 + col] = f2b(vv);
      }
}

// ---------------------------------------------------------------------------
// Kernel 4: RoPE + [B,S,H,DK]->[B,H,S,DK] relayout. Q scaled by
// (1/8)*log2(e) so attention softmax can run in exp2 domain.
// ---------------------------------------------------------------------------
__global__ __launch_bounds__(256) void k_rope(
    const u16* __restrict__ tq, const u16* __restrict__ tk,
    const float* __restrict__ cosT, const float* __restrict__ sinT,
    u16* __restrict__ Qr, u16* __restrict__ Kr) {
  int idx = blockIdx.x * 256 + threadIdx.x;  // 0 .. 4Mi
  int t = idx >> 21;
  int r = idx & ((1 << 21) - 1);
  int j = r & 31;
  int h = (r >> 5) & 15;
  int s = (r >> 9) & 2047;
  int b = (r >> 20) & 1;

  const u16* in = t ? tk : tq;
  u16* out = t ? Kr : Qr;

  int bi = (b * Sdim + s) * Ddim + h * 64 + j;
  float x1 = b2f(in[bi]);
  float x2 = b2f(in[bi + 32]);
  float cv = cosT[s * 32 + j];
  float sv = sinT[s * 32 + j];
  float o1 = x1 * cv - x2 * sv;
  float o2 = x2 * cv + x1 * sv;
  if (t == 0) { o1 *= 0.18033688011112042f; o2 *= 0.18033688011112042f; } // 0.125*log2e
  int bo = ((b * Hdim + h) * Sdim + s) * 64 + j;
  out[bo] = f2b(o1);
  out[bo + 32] = f2b(o2);
}

// ---------------------------------------------------------------------------
// Kernel 5: V relayout+transpose: tmpV [B,S,H*DK] -> Vt [BH, DK, S] with keys
// permuted within each 32-chunk into MFMA kappa-order: pos = (kap&15)>>2 *8
// + (kap>>4)*4 + (kap&3), so an attention lane reads its 8 keys as one b128.
// ---------------------------------------------------------------------------
__global__ __launch_bounds__(256) void k_transv(const u16* __restrict__ tv, u16* __restrict__ Vt) {
  __shared__ u16 tl[64][72];
  const int bh = blockIdx.y;
  const int b = bh >> 4, h = bh & 15;
  const int s0 = blockIdx.x * 64;
  const int tid = threadIdx.x;
#pragma unroll
  for (int p = 0; p < 4; ++p) {
    int row = p * 16 + (tid >> 4);
    int dc = (tid & 15) * 4;
    ushort4 val = *(const ushort4*)(tv + (b * Sdim + s0 + row) * Ddim + h * 64 + dc);
    *(ushort4*)&tl[row][dc] = val;
  }
  __syncthreads();
#pragma unroll
  for (int p = 0; p < 4; ++p) {
    int dr = p * 16 + (tid >> 4);
    int sc = (tid & 15) * 4;
    ushort4 o;
    o.x = tl[sc + 0][dr];
    o.y = tl[sc + 1][dr];
    o.z = tl[sc + 2][dr];
    o.w = tl[sc + 3][dr];
    int s_abs = s0 + sc;
    int cch = s_abs >> 5;
    int kap = s_abs & 31;
    int g2 = (kap >> 2) & 3;
    int seg = kap >> 4;
    *(ushort4*)(Vt + (size_t)(bh * 64 + dr) * Sdim + (cch << 5) + (g2 << 3) + (seg << 2)) = o;
  }
}

// ---------------------------------------------------------------------------
// Kernel 6: causal flash attention, swapped-operand, 32 q-rows per wave
// (two 16-row tiles sharing all K/V loads), register double-buffered K/V
// prefetch, exp2-domain softmax with defer-max (THR = 11.5 in log2 units).
// One wave per block; grid ordered heavy-first for load balance.
// ---------------------------------------------------------------------------
__device__ __forceinline__ void loadKf(const u16* Kp, int j0, int cc, int g, bf16x8 kf[4]) {
  const u16* kp = Kp + (j0 + cc) * 64 + g * 8;
  kf[0] = *(const bf16x8*)(kp);
  kf[1] = *(const bf16x8*)(kp + 32);
  kf[2] = *(const bf16x8*)(kp + 1024);
  kf[3] = *(const bf16x8*)(kp + 1056);
}
__device__ __forceinline__ void loadVf(const u16* Vp, int j0, int cc, int g, bf16x8 vf[4]) {
#pragma unroll
  for (int dc = 0; dc < 4; ++dc)
    vf[dc] = *(const bf16x8*)(Vp + (dc * 16 + cc) * Sdim + j0 + g * 8);
}

template <bool MASKED>
__device__ __forceinline__ void attn_chunk32(
    int cc, int g,
    const bf16x8 kf[4], const bf16x8 vf[4], const bf16x8 qf[4],
    float& mold0, float& mold1, float& lsum0, float& lsum1,
    f32x4 ot0[4], f32x4 ot1[4]) {
  f32x4 sA0 = {}, sB0 = {}, sA1 = {}, sB1 = {};
  sA0 = mfma_bf16(kf[0], qf[0], sA0);
  sA0 = mfma_bf16(kf[1], qf[1], sA0);
  sB0 = mfma_bf16(kf[2], qf[0], sB0);
  sB0 = mfma_bf16(kf[3], qf[1], sB0);
  sA1 = mfma_bf16(kf[0], qf[2], sA1);
  sA1 = mfma_bf16(kf[1], qf[3], sA1);
  sB1 = mfma_bf16(kf[2], qf[2], sB1);
  sB1 = mfma_bf16(kf[3], qf[3], sB1);

  // diagonal chunk (j0 == qrow0): tile0 row cc allows kappa<=cc (seg1 fully
  // masked); tile1 row 16+cc allows seg0 fully, seg1 iff g*4+r <= cc.
  float p0[8], p1[8];
#pragma unroll
  for (int r = 0; r < 4; ++r) {
    float a0 = sA0[r], b0v = sB0[r], a1 = sA1[r], b1v = sB1[r];
    if (MASKED) {
      const int ka = g * 4 + r;
      a0  = (ka <= cc) ? a0  : -30000.0f;
      b0v = -30000.0f;
      b1v = (ka <= cc) ? b1v : -30000.0f;
    }
    p0[r] = a0; p0[r + 4] = b0v;
    p1[r] = a1; p1[r + 4] = b1v;
  }

  float m0 = fmaxf(fmaxf(fmaxf(p0[0], p0[1]), fmaxf(p0[2], p0[3])),
                   fmaxf(fmaxf(p0[4], p0[5]), fmaxf(p0[6], p0[7])));
  float m1 = fmaxf(fmaxf(fmaxf(p1[0], p1[1]), fmaxf(p1[2], p1[3])),
                   fmaxf(fmaxf(p1[4], p1[5]), fmaxf(p1[6], p1[7])));
  m0 = fmaxf(m0, __shfl_xor(m0, 16));
  m0 = fmaxf(m0, __shfl_xor(m0, 32));
  m1 = fmaxf(m1, __shfl_xor(m1, 16));
  m1 = fmaxf(m1, __shfl_xor(m1, 32));

  if (!__all((m0 <= mold0 + 11.5f) && (m1 <= mold1 + 11.5f))) {
    const float mn0 = fmaxf(mold0, m0), mn1 = fmaxf(mold1, m1);
    const float al0 = exp2f(mold0 - mn0), al1 = exp2f(mold1 - mn1);
    mold0 = mn0; mold1 = mn1;
    lsum0 *= al0; lsum1 *= al1;
#pragma unroll
    for (int dc = 0; dc < 4; ++dc) { ot0[dc] *= al0; ot1[dc] *= al1; }
  }

  float rs0 = 0.f, rs1 = 0.f;
  union { bf16x8 v; u16 s[8]; } pu0, pu1;
#pragma unroll
  for (int j = 0; j < 8; ++j) {
    float e0 = exp2f(p0[j] - mold0);
    float e1 = exp2f(p1[j] - mold1);
    rs0 += e0; rs1 += e1;
    pu0.s[j] = f2b(e0);
    pu1.s[j] = f2b(e1);
  }
  lsum0 += rs0; lsum1 += rs1;
#pragma unroll
  for (int dc = 0; dc < 4; ++dc) {
    ot0[dc] = mfma_bf16(vf[dc], pu0.v, ot0[dc]);
    ot1[dc] = mfma_bf16(vf[dc], pu1.v, ot1[dc]);
  }
}

__global__ __launch_bounds__(64, 2) void k_attn(
    const u16* __restrict__ Qr, const u16* __restrict__ Kr,
    const u16* __restrict__ Vt, u16* __restrict__ Oc) {
  const int x = blockIdx.x;          // 0..2047
  const int bh = x & 31;
  const int u = 63 - (x >> 5);       // heavy blocks dispatched first
  const int b = bh >> 4, h = bh & 15;
  const int lane = threadIdx.x;
  const int g = lane >> 4, cc = lane & 15;
  const int qrow0 = u * 32;

  const u16* Kp = Kr + bh * (Sdim * 64);
  const u16* Vp = Vt + bh * (64 * Sdim);
  const u16* Qp = Qr + (size_t)(bh * Sdim + qrow0) * 64;

  bf16x8 qf[4];
  qf[0] = *(const bf16x8*)(Qp + cc * 64 + g * 8);
  qf[1] = *(const bf16x8*)(Qp + cc * 64 + g * 8 + 32);
  qf[2] = *(const bf16x8*)(Qp + (16 + cc) * 64 + g * 8);
  qf[3] = *(const bf16x8*)(Qp + (16 + cc) * 64 + g * 8 + 32);

  float mold0 = -1e30f, mold1 = -1e30f, lsum0 = 0.f, lsum1 = 0.f;
  f32x4 ot0[4] = {}, ot1[4] = {};

  const int n = u + 1;   // chunks; last (kb = u) is the diagonal (masked)
  bf16x8 kA[4], vA[4], kB[4], vB[4];
  loadKf(Kp, 0, cc, g, kA);
  loadVf(Vp, 0, cc, g, vA);

  int kb = 0;
  while (kb + 2 <= n - 1) {
    loadKf(Kp, (kb + 1) * 32, cc, g, kB);
    loadVf(Vp, (kb + 1) * 32, cc, g, vB);
    attn_chunk32<false>(cc, g, kA, vA, qf, mold0, mold1, lsum0, lsum1, ot0, ot1);
    loadKf(Kp, (kb + 2) * 32, cc, g, kA);
    loadVf(Vp, (kb + 2) * 32, cc, g, vA);
    attn_chunk32<false>(cc, g, kB, vB, qf, mold0, mold1, lsum0, lsum1, ot0, ot1);
    kb += 2;
  }
  if (kb + 1 <= n - 1) {
    loadKf(Kp, (kb + 1) * 32, cc, g, kB);
    loadVf(Vp, (kb + 1) * 32, cc, g, vB);
    attn_chunk32<false>(cc, g, kA, vA, qf, mold0, mold1, lsum0, lsum1, ot0, ot1);
    attn_chunk32<true>(cc, g, kB, vB, qf, mold0, mold1, lsum0, lsum1, ot0, ot1);
  } else {
    attn_chunk32<true>(cc, g, kA, vA, qf, mold0, mold1, lsum0, lsum1, ot0, ot1);
  }

  lsum0 += __shfl_xor(lsum0, 16);
  lsum0 += __shfl_xor(lsum0, 32);
  lsum1 += __shfl_xor(lsum1, 16);
  lsum1 += __shfl_xor(lsum1, 32);
  const float rl0 = 1.0f / lsum0, rl1 = 1.0f / lsum1;

  u16* dst0 = Oc + (size_t)(b * Sdim + qrow0 + cc) * Ddim + h * 64 + g * 4;
  u16* dst1 = dst0 + 16 * Ddim;
#pragma unroll
  for (int dc = 0; dc < 4; ++dc) {
    ushort4 o0, o1;
    o0.x = f2b(ot0[dc][0] * rl0);
    o0.y = f2b(ot0[dc][1] * rl0);
    o0.z = f2b(ot0[dc][2] * rl0);
    o0.w = f2b(ot0[dc][3] * rl0);
    o1.x = f2b(ot1[dc][0] * rl1);
    o1.y = f2b(ot1[dc][1] * rl1);
    o1.z = f2b(ot1[dc][2] * rl1);
    o1.w = f2b(ot1[dc][3] * rl1);
    *(ushort4*)(dst0 + dc * 16) = o0;
    *(ushort4*)(dst1 + dc * 16) = o1;
  }
}

// ---------------------------------------------------------------------------
extern "C" void kernel_launch(void* const* d_in, const int* in_sizes, int n_in,
                              void* d_out, int out_size, void* d_ws, size_t ws_size,
                              hipStream_t stream) {
  const float* q = (const float*)d_in[0];
  const float* k = (const float*)d_in[1];
  const float* v = (const float*)d_in[2];
  const float* wq = (const float*)d_in[3];
  const float* wk = (const float*)d_in[4];
  const float* wv = (const float*)d_in[5];
  const float* wo = (const float*)d_in[6];
  float* out = (float*)d_out;

  uint8_t* ws = (uint8_t*)d_ws;
  const size_t MiB = 1ull << 20;
  u16* qb  = (u16*)(ws + 0 * MiB);
  u16* kb  = (u16*)(ws + 8 * MiB);
  u16* vb  = (u16*)(ws + 16 * MiB);
  u16* wqb = (u16*)(ws + 24 * MiB);
  u16* wkb = (u16*)(ws + 26 * MiB);
  u16* wvb = (u16*)(ws + 28 * MiB);
  u16* wob = (u16*)(ws + 30 * MiB);
  u16* tQ  = (u16*)(ws + 32 * MiB);
  u16* tK  = (u16*)(ws + 40 * MiB);
  u16* tV  = (u16*)(ws + 48 * MiB);
  u16* Qr  = (u16*)(ws + 56 * MiB);
  u16* Kr  = (u16*)(ws + 64 * MiB);
  u16* Vt  = (u16*)(ws + 72 * MiB);
  u16* Oc  = (u16*)(ws + 80 * MiB);
  float* cosT = (float*)(ws + 88 * MiB);
  float* sinT = (float*)(ws + 88 * MiB + 256 * 1024);

  k_convert<<<16384, 256, 0, stream>>>(q, k, v, wq, wk, wv, wo,
                                       qb, kb, vb, wqb, wkb, wvb, wob);
  k_ropetab<<<256, 256, 0, stream>>>(cosT, sinT);
  k_gemm<0><<<dim3(32, 8, 3), 256, 0, stream>>>(qb, wqb, tQ, kb, wkb, tK, vb, wvb, tV);
  k_rope<<<16384, 256, 0, stream>>>(tQ, tK, cosT, sinT, Qr, Kr);
  k_transv<<<dim3(32, 32), 256, 0, stream>>>(tV, Vt);
  k_attn<<<2048, 64, 0, stream>>>(Qr, Kr, Vt, Oc);
  k_gemm<1><<<dim3(32, 8, 1), 256, 0, stream>>>(Oc, wob, out, Oc, wob, out, Oc, wob, out);
}

// Round 4
// 152.042 us; speedup vs baseline: 2.0765x; 1.0921x over previous
//
#include <hip/hip_runtime.h>
#include <hip/hip_bf16.h>
#include <stdint.h>

#define Bdim 2
#define Sdim 2048
#define Ddim 1024
#define Hdim 16
// DK = 64, BH = 32, M = B*S = 4096

typedef unsigned short u16;
typedef __bf16 bf16x8 __attribute__((ext_vector_type(8)));
typedef float f32x4 __attribute__((ext_vector_type(4)));

__device__ __forceinline__ u16 f2b(float x) {
  __hip_bfloat16 h = __float2bfloat16(x);
  return __builtin_bit_cast(u16, h);
}
__device__ __forceinline__ float b2f(u16 u) {
  return __bfloat162float(__builtin_bit_cast(__hip_bfloat16, u));
}
__device__ __forceinline__ f32x4 mfma_bf16(bf16x8 a, bf16x8 b, f32x4 c) {
  return __builtin_amdgcn_mfma_f32_16x16x32_bf16(a, b, c, 0, 0, 0);
}
__device__ __forceinline__ void gload_lds16(const u16* gp, u16* lp) {
  __builtin_amdgcn_global_load_lds(
      (const __attribute__((address_space(1))) void*)gp,
      (__attribute__((address_space(3))) void*)lp, 16, 0, 0);
}

// ---------------------------------------------------------------------------
// Kernel 1: fp32 -> bf16 conversion of q,k,v and the 4 weights.
// ---------------------------------------------------------------------------
__global__ __launch_bounds__(256) void k_convert(
    const float* __restrict__ q, const float* __restrict__ k, const float* __restrict__ v,
    const float* __restrict__ wq, const float* __restrict__ wk,
    const float* __restrict__ wv, const float* __restrict__ wo,
    u16* __restrict__ qb, u16* __restrict__ kb, u16* __restrict__ vb,
    u16* __restrict__ wqb, u16* __restrict__ wkb, u16* __restrict__ wvb, u16* __restrict__ wob) {
  int i = (blockIdx.x * 256 + threadIdx.x) * 4;
  const float* src;
  u16* dst;
  int off;
  if (i < 12582912) {              // 3 * 4Mi
    int s = i >> 22;
    off = i - (s << 22);
    src = (s == 0) ? q : ((s == 1) ? k : v);
    dst = (s == 0) ? qb : ((s == 1) ? kb : vb);
  } else {
    int j = i - 12582912;
    int s = j >> 20;
    off = j - (s << 20);
    src = (s == 0) ? wq : ((s == 1) ? wk : ((s == 2) ? wv : wo));
    dst = (s == 0) ? wqb : ((s == 1) ? wkb : ((s == 2) ? wvb : wob));
  }
  float4 f = *(const float4*)(src + off);
  ushort4 o;
  o.x = f2b(f.x); o.y = f2b(f.y); o.z = f2b(f.z); o.w = f2b(f.w);
  *(ushort4*)(dst + off) = o;
}

// ---------------------------------------------------------------------------
// Kernel 2: RoPE cos/sin table, [S][32] each, fp32.
// ---------------------------------------------------------------------------
__global__ __launch_bounds__(256) void k_ropetab(float* __restrict__ cosT, float* __restrict__ sinT) {
  int i = blockIdx.x * 256 + threadIdx.x;   // 0 .. 65536
  int s = i >> 5, j = i & 31;
  float invf = expf(-(float)j * 0.28782313662425574f);  // ln(1e4)/32
  float ang = (float)s * invf;
  float sn, cs;
  sincosf(ang, &sn, &cs);
  cosT[i] = cs;
  sinT[i] = sn;
}

// ---------------------------------------------------------------------------
// Kernel 3: GEMM  C[M,N] = A[M,K] @ W[N,K]^T  (bf16 in, fp32 accum).
// 128x128 tile, BK=32, 4 waves, global_load_lds width=16 staging.
// ---------------------------------------------------------------------------
template <int OUTF>
__global__ __launch_bounds__(256) void k_gemm(
    const u16* __restrict__ A0, const u16* __restrict__ W0, void* __restrict__ O0,
    const u16* __restrict__ A1, const u16* __restrict__ W1, void* __restrict__ O1,
    const u16* __restrict__ A2, const u16* __restrict__ W2, void* __restrict__ O2) {
  const u16* A = (blockIdx.z == 0) ? A0 : ((blockIdx.z == 1) ? A1 : A2);
  const u16* W = (blockIdx.z == 0) ? W0 : ((blockIdx.z == 1) ? W1 : W2);
  void* O = (blockIdx.z == 0) ? O0 : ((blockIdx.z == 1) ? O1 : O2);

  __shared__ u16 As[128 * 32];
  __shared__ u16 Bs[128 * 32];

  const int tid = threadIdx.x;
  const int wave = tid >> 6, lane = tid & 63;
  const int g = lane >> 4, cc = lane & 15;
  const int wm = wave >> 1, wn = wave & 1;
  const int row0 = blockIdx.x * 128, col0 = blockIdx.y * 128;

  const int srow = wave * 16 + (lane >> 2);
  const int sseg = (lane & 3) * 8;
  const u16* Ap  = A + (size_t)(row0 + srow) * 1024 + sseg;
  const u16* Ap2 = Ap + 64 * 1024;
  const u16* Wp  = W + (size_t)(col0 + srow) * 1024 + sseg;
  const u16* Wp2 = Wp + 64 * 1024;
  u16* asl  = &As[wave * 512];
  u16* asl2 = &As[2048 + wave * 512];
  u16* bsl  = &Bs[wave * 512];
  u16* bsl2 = &Bs[2048 + wave * 512];

  f32x4 acc[4][4] = {};

  for (int k0 = 0; k0 < 1024; k0 += 32) {
    __syncthreads();
    gload_lds16(Ap + k0, asl);
    gload_lds16(Ap2 + k0, asl2);
    gload_lds16(Wp + k0, bsl);
    gload_lds16(Wp2 + k0, bsl2);
    __syncthreads();
    bf16x8 af[4], bfv[4];
#pragma unroll
    for (int mi = 0; mi < 4; ++mi)
      af[mi] = *(const bf16x8*)&As[(wm * 64 + mi * 16 + cc) * 32 + g * 8];
#pragma unroll
    for (int ni = 0; ni < 4; ++ni)
      bfv[ni] = *(const bf16x8*)&Bs[(wn * 64 + ni * 16 + cc) * 32 + g * 8];
#pragma unroll
    for (int mi = 0; mi < 4; ++mi)
#pragma unroll
      for (int ni = 0; ni < 4; ++ni)
        acc[mi][ni] = mfma_bf16(af[mi], bfv[ni], acc[mi][ni]);
  }

#pragma unroll
  for (int mi = 0; mi < 4; ++mi)
#pragma unroll
    for (int ni = 0; ni < 4; ++ni)
#pragma unroll
      for (int r = 0; r < 4; ++r) {
        const int row = row0 + wm * 64 + mi * 16 + g * 4 + r;
        const int col = col0 + wn * 64 + ni * 16 + cc;
        const float vv = acc[mi][ni][r];
        if (OUTF)
          ((float*)O)[row * 1024 + col] = vv;
        else
          ((u16*)O)[row * 1024 + col] = f2b(vv);
      }
}

// ---------------------------------------------------------------------------
// Kernel 4: RoPE + [B,S,H,DK]->[B,H,S,DK] relayout. Q scaled by
// (1/8)*log2(e) so attention softmax can run in exp2 domain.
// ---------------------------------------------------------------------------
__global__ __launch_bounds__(256) void k_rope(
    const u16* __restrict__ tq, const u16* __restrict__ tk,
    const float* __restrict__ cosT, const float* __restrict__ sinT,
    u16* __restrict__ Qr, u16* __restrict__ Kr) {
  int idx = blockIdx.x * 256 + threadIdx.x;  // 0 .. 4Mi
  int t = idx >> 21;
  int r = idx & ((1 << 21) - 1);
  int j = r & 31;
  int h = (r >> 5) & 15;
  int s = (r >> 9) & 2047;
  int b = (r >> 20) & 1;

  const u16* in = t ? tk : tq;
  u16* out = t ? Kr : Qr;

  int bi = (b * Sdim + s) * Ddim + h * 64 + j;
  float x1 = b2f(in[bi]);
  float x2 = b2f(in[bi + 32]);
  float cv = cosT[s * 32 + j];
  float sv = sinT[s * 32 + j];
  float o1 = x1 * cv - x2 * sv;
  float o2 = x2 * cv + x1 * sv;
  if (t == 0) { o1 *= 0.18033688011112042f; o2 *= 0.18033688011112042f; } // 0.125*log2e
  int bo = ((b * Hdim + h) * Sdim + s) * 64 + j;
  out[bo] = f2b(o1);
  out[bo + 32] = f2b(o2);
}

// ---------------------------------------------------------------------------
// Kernel 5: V relayout+transpose: tmpV [B,S,H*DK] -> Vt [BH, DK, S] with keys
// permuted within each 32-chunk into MFMA kappa-order: pos = (kap&15)>>2 *8
// + (kap>>4)*4 + (kap&3), so an attention lane reads its 8 keys as one b128.
// ---------------------------------------------------------------------------
__global__ __launch_bounds__(256) void k_transv(const u16* __restrict__ tv, u16* __restrict__ Vt) {
  __shared__ u16 tl[64][72];
  const int bh = blockIdx.y;
  const int b = bh >> 4, h = bh & 15;
  const int s0 = blockIdx.x * 64;
  const int tid = threadIdx.x;
#pragma unroll
  for (int p = 0; p < 4; ++p) {
    int row = p * 16 + (tid >> 4);
    int dc = (tid & 15) * 4;
    ushort4 val = *(const ushort4*)(tv + (b * Sdim + s0 + row) * Ddim + h * 64 + dc);
    *(ushort4*)&tl[row][dc] = val;
  }
  __syncthreads();
#pragma unroll
  for (int p = 0; p < 4; ++p) {
    int dr = p * 16 + (tid >> 4);
    int sc = (tid & 15) * 4;
    ushort4 o;
    o.x = tl[sc + 0][dr];
    o.y = tl[sc + 1][dr];
    o.z = tl[sc + 2][dr];
    o.w = tl[sc + 3][dr];
    int s_abs = s0 + sc;
    int cch = s_abs >> 5;
    int kap = s_abs & 31;
    int g2 = (kap >> 2) & 3;
    int seg = kap >> 4;
    *(ushort4*)(Vt + (size_t)(bh * 64 + dr) * Sdim + (cch << 5) + (g2 << 3) + (seg << 2)) = o;
  }
}

// ---------------------------------------------------------------------------
// Kernel 6: causal flash attention, LDS-staged K/V with 2-phase pipeline.
// Block = 256 threads = 4 waves = 128 q-rows of one (b,h); each wave owns a
// 32-row sub-tile (two 16-row MFMA tiles). Per 32-key chunk: one 4KB K-stage
// + one 4KB V-stage via global_load_lds (2 instrs/thread), double-buffered;
// barrier(drain t) -> issue stage t+1 -> compute t (stage latency hides
// under 4-wave compute). LDS reads XOR-swizzled (pre-swizzled global source,
// T21): K block s = g^(cc&7), V block s = g^((cc>>1)&3) -> 2-way (free).
// Softmax: swapped-operand in-register, exp2 domain, defer-max THR=11.5.
// Block remap: CU pairs (t5, t5+8) get i summing to 15 -> balanced work.
// ---------------------------------------------------------------------------
template <bool MASKED>
__device__ __forceinline__ void attn_lds(
    const u16* __restrict__ kl, const u16* __restrict__ vl, int cc, int g,
    const bf16x8 qf[4],
    float& mold0, float& mold1, float& lsum0, float& lsum1,
    f32x4 ot0[4], f32x4 ot1[4]) {
  const int ksw = cc & 7;
  const int vsw = (cc >> 1) & 3;
  bf16x8 kf0 = *(const bf16x8*)&kl[cc * 64 + ((g ^ ksw) * 8)];
  bf16x8 kf1 = *(const bf16x8*)&kl[cc * 64 + (((g + 4) ^ ksw) * 8)];
  bf16x8 kf2 = *(const bf16x8*)&kl[(16 + cc) * 64 + ((g ^ ksw) * 8)];
  bf16x8 kf3 = *(const bf16x8*)&kl[(16 + cc) * 64 + (((g + 4) ^ ksw) * 8)];

  f32x4 sA0 = {}, sB0 = {}, sA1 = {}, sB1 = {};
  sA0 = mfma_bf16(kf0, qf[0], sA0);
  sA0 = mfma_bf16(kf1, qf[1], sA0);
  sB0 = mfma_bf16(kf2, qf[0], sB0);
  sB0 = mfma_bf16(kf3, qf[1], sB0);
  sA1 = mfma_bf16(kf0, qf[2], sA1);
  sA1 = mfma_bf16(kf1, qf[3], sA1);
  sB1 = mfma_bf16(kf2, qf[2], sB1);
  sB1 = mfma_bf16(kf3, qf[3], sB1);

  bf16x8 vf0 = *(const bf16x8*)&vl[(0 * 16 + cc) * 32 + ((g ^ vsw) * 8)];
  bf16x8 vf1 = *(const bf16x8*)&vl[(1 * 16 + cc) * 32 + ((g ^ vsw) * 8)];
  bf16x8 vf2 = *(const bf16x8*)&vl[(2 * 16 + cc) * 32 + ((g ^ vsw) * 8)];
  bf16x8 vf3 = *(const bf16x8*)&vl[(3 * 16 + cc) * 32 + ((g ^ vsw) * 8)];

  // diagonal chunk (j0 == wave qrow0): tile0 row cc allows kappa<=cc (seg1
  // fully masked); tile1 row 16+cc allows seg0 fully, seg1 iff g*4+r <= cc.
  float p0[8], p1[8];
#pragma unroll
  for (int r = 0; r < 4; ++r) {
    float a0 = sA0[r], b0v = sB0[r], a1 = sA1[r], b1v = sB1[r];
    if (MASKED) {
      const int ka = g * 4 + r;
      a0  = (ka <= cc) ? a0  : -30000.0f;
      b0v = -30000.0f;
      b1v = (ka <= cc) ? b1v : -30000.0f;
    }
    p0[r] = a0; p0[r + 4] = b0v;
    p1[r] = a1; p1[r + 4] = b1v;
  }

  float m0 = fmaxf(fmaxf(fmaxf(p0[0], p0[1]), fmaxf(p0[2], p0[3])),
                   fmaxf(fmaxf(p0[4], p0[5]), fmaxf(p0[6], p0[7])));
  float m1 = fmaxf(fmaxf(fmaxf(p1[0], p1[1]), fmaxf(p1[2], p1[3])),
                   fmaxf(fmaxf(p1[4], p1[5]), fmaxf(p1[6], p1[7])));
  m0 = fmaxf(m0, __shfl_xor(m0, 16));
  m0 = fmaxf(m0, __shfl_xor(m0, 32));
  m1 = fmaxf(m1, __shfl_xor(m1, 16));
  m1 = fmaxf(m1, __shfl_xor(m1, 32));

  if (!__all((m0 <= mold0 + 11.5f) && (m1 <= mold1 + 11.5f))) {
    const float mn0 = fmaxf(mold0, m0), mn1 = fmaxf(mold1, m1);
    const float al0 = exp2f(mold0 - mn0), al1 = exp2f(mold1 - mn1);
    mold0 = mn0; mold1 = mn1;
    lsum0 *= al0; lsum1 *= al1;
#pragma unroll
    for (int dc = 0; dc < 4; ++dc) { ot0[dc] *= al0; ot1[dc] *= al1; }
  }

  float rs0 = 0.f, rs1 = 0.f;
  union { bf16x8 v; u16 s[8]; } pu0, pu1;
#pragma unroll
  for (int j = 0; j < 8; ++j) {
    float e0 = exp2f(p0[j] - mold0);
    float e1 = exp2f(p1[j] - mold1);
    rs0 += e0; rs1 += e1;
    pu0.s[j] = f2b(e0);
    pu1.s[j] = f2b(e1);
  }
  lsum0 += rs0; lsum1 += rs1;
  ot0[0] = mfma_bf16(vf0, pu0.v, ot0[0]);
  ot1[0] = mfma_bf16(vf0, pu1.v, ot1[0]);
  ot0[1] = mfma_bf16(vf1, pu0.v, ot0[1]);
  ot1[1] = mfma_bf16(vf1, pu1.v, ot1[1]);
  ot0[2] = mfma_bf16(vf2, pu0.v, ot0[2]);
  ot1[2] = mfma_bf16(vf2, pu1.v, ot1[2]);
  ot0[3] = mfma_bf16(vf3, pu0.v, ot0[3]);
  ot1[3] = mfma_bf16(vf3, pu1.v, ot1[3]);
}

__global__ __launch_bounds__(256, 2) void k_attn(
    const u16* __restrict__ Qr, const u16* __restrict__ Kr,
    const u16* __restrict__ Vt, u16* __restrict__ Oc) {
  __shared__ u16 Kl[2][2048];   // [buf][32 keys x 64 d]  (swizzled cols)
  __shared__ u16 Vl[2][2048];   // [buf][64 d x 32 keys]  (swizzled segs)

  const int x = blockIdx.x;          // 0..511
  const int bh = x & 31;
  const int t5 = x >> 5;             // 0..15
  const int i = (t5 < 8) ? (15 - 2 * t5) : (2 * (t5 - 8));  // q-block of 128 rows
  const int b = bh >> 4, h = bh & 15;
  const int tid = threadIdx.x;
  const int w = tid >> 6;
  const int lane = tid & 63;
  const int g = lane >> 4, cc = lane & 15;

  const int qrow0 = i * 128 + w * 32;
  const int myDiag = 4 * i + w;      // this wave's diagonal chunk index
  const int NC = 4 * i + 4;          // chunks this block stages

  const u16* Kp = Kr + (size_t)bh * (Sdim * 64);
  const u16* Vp = Vt + (size_t)bh * (64 * Sdim);
  const u16* Qp = Qr + (size_t)(bh * Sdim + qrow0) * 64;

  // per-thread stage sources (chunk 0), pre-swizzled (T21)
  const int krow = lane >> 3;              // row within wave's 8 K-rows
  const int kseg = lane & 7;
  const u16* kSrc = Kp + (size_t)(w * 8 + krow) * 64 + ((kseg ^ krow) * 8);
  const int vrow = w * 16 + (lane >> 2);   // dk row
  const int vseg = lane & 3;
  const u16* vSrc = Vp + (size_t)vrow * Sdim + ((vseg ^ ((lane >> 3) & 3)) * 8);

  u16* kD[2] = { &Kl[0][w * 512], &Kl[1][w * 512] };
  u16* vD[2] = { &Vl[0][w * 512], &Vl[1][w * 512] };

  bf16x8 qf[4];
  qf[0] = *(const bf16x8*)(Qp + cc * 64 + g * 8);
  qf[1] = *(const bf16x8*)(Qp + cc * 64 + g * 8 + 32);
  qf[2] = *(const bf16x8*)(Qp + (16 + cc) * 64 + g * 8);
  qf[3] = *(const bf16x8*)(Qp + (16 + cc) * 64 + g * 8 + 32);

  float mold0 = -1e30f, mold1 = -1e30f, lsum0 = 0.f, lsum1 = 0.f;
  f32x4 ot0[4] = {}, ot1[4] = {};

  // prologue: stage chunk 0 into buf 0
  gload_lds16(kSrc, kD[0]);
  gload_lds16(vSrc, vD[0]);

  for (int t = 0; t < NC; ++t) {
    __syncthreads();                 // drains stage(t); all waves' data in LDS
    if (t + 1 < NC) {                // issue stage(t+1) -- latency hidden by compute(t)
      const int nb = (t + 1) & 1;
      gload_lds16(kSrc + (size_t)(t + 1) * 2048, kD[nb]);
      gload_lds16(vSrc + (t + 1) * 32, vD[nb]);
    }
    if (t <= myDiag) {
      const u16* kl = (t & 1) ? &Kl[1][0] : &Kl[0][0];
      const u16* vl = (t & 1) ? &Vl[1][0] : &Vl[0][0];
      if (t == myDiag)
        attn_lds<true>(kl, vl, cc, g, qf, mold0, mold1, lsum0, lsum1, ot0, ot1);
      else
        attn_lds<false>(kl, vl, cc, g, qf, mold0, mold1, lsum0, lsum1, ot0, ot1);
    }
  }

  lsum0 += __shfl_xor(lsum0, 16);
  lsum0 += __shfl_xor(lsum0, 32);
  lsum1 += __shfl_xor(lsum1, 16);
  lsum1 += __shfl_xor(lsum1, 32);
  const float rl0 = 1.0f / lsum0, rl1 = 1.0f / lsum1;

  u16* dst0 = Oc + (size_t)(b * Sdim + qrow0 + cc) * Ddim + h * 64 + g * 4;
  u16* dst1 = dst0 + 16 * Ddim;
#pragma unroll
  for (int dc = 0; dc < 4; ++dc) {
    ushort4 o0, o1;
    o0.x = f2b(ot0[dc][0] * rl0);
    o0.y = f2b(ot0[dc][1] * rl0);
    o0.z = f2b(ot0[dc][2] * rl0);
    o0.w = f2b(ot0[dc][3] * rl0);
    o1.x = f2b(ot1[dc][0] * rl1);
    o1.y = f2b(ot1[dc][1] * rl1);
    o1.z = f2b(ot1[dc][2] * rl1);
    o1.w = f2b(ot1[dc][3] * rl1);
    *(ushort4*)(dst0 + dc * 16) = o0;
    *(ushort4*)(dst1 + dc * 16) = o1;
  }
}

// ---------------------------------------------------------------------------
extern "C" void kernel_launch(void* const* d_in, const int* in_sizes, int n_in,
                              void* d_out, int out_size, void* d_ws, size_t ws_size,
                              hipStream_t stream) {
  const float* q = (const float*)d_in[0];
  const float* k = (const float*)d_in[1];
  const float* v = (const float*)d_in[2];
  const float* wq = (const float*)d_in[3];
  const float* wk = (const float*)d_in[4];
  const float* wv = (const float*)d_in[5];
  const float* wo = (const float*)d_in[6];
  float* out = (float*)d_out;

  uint8_t* ws = (uint8_t*)d_ws;
  const size_t MiB = 1ull << 20;
  u16* qb  = (u16*)(ws + 0 * MiB);
  u16* kb  = (u16*)(ws + 8 * MiB);
  u16* vb  = (u16*)(ws + 16 * MiB);
  u16* wqb = (u16*)(ws + 24 * MiB);
  u16* wkb = (u16*)(ws + 26 * MiB);
  u16* wvb = (u16*)(ws + 28 * MiB);
  u16* wob = (u16*)(ws + 30 * MiB);
  u16* tQ  = (u16*)(ws + 32 * MiB);
  u16* tK  = (u16*)(ws + 40 * MiB);
  u16* tV  = (u16*)(ws + 48 * MiB);
  u16* Qr  = (u16*)(ws + 56 * MiB);
  u16* Kr  = (u16*)(ws + 64 * MiB);
  u16* Vt  = (u16*)(ws + 72 * MiB);
  u16* Oc  = (u16*)(ws + 80 * MiB);
  float* cosT = (float*)(ws + 88 * MiB);
  float* sinT = (float*)(ws + 88 * MiB + 256 * 1024);

  k_convert<<<16384, 256, 0, stream>>>(q, k, v, wq, wk, wv, wo,
                                       qb, kb, vb, wqb, wkb, wvb, wob);
  k_ropetab<<<256, 256, 0, stream>>>(cosT, sinT);
  k_gemm<0><<<dim3(32, 8, 3), 256, 0, stream>>>(qb, wqb, tQ, kb, wkb, tK, vb, wvb, tV);
  k_rope<<<16384, 256, 0, stream>>>(tQ, tK, cosT, sinT, Qr, Kr);
  k_transv<<<dim3(32, 32), 256, 0, stream>>>(tV, Vt);
  k_attn<<<512, 256, 0, stream>>>(Qr, Kr, Vt, Oc);
  k_gemm<1><<<dim3(32, 8, 1), 256, 0, stream>>>(Oc, wob, out, Oc, wob, out, Oc, wob, out);
}

// Round 5
// 149.674 us; speedup vs baseline: 2.1093x; 1.0158x over previous
//
#include <hip/hip_runtime.h>
#include <hip/hip_bf16.h>
#include <stdint.h>

#define Bdim 2
#define Sdim 2048
#define Ddim 1024
#define Hdim 16
// DK = 64, BH = 32, M = B*S = 4096

typedef unsigned short u16;
typedef __bf16 bf16x8 __attribute__((ext_vector_type(8)));
typedef float f32x4 __attribute__((ext_vector_type(4)));

__device__ __forceinline__ u16 f2b(float x) {
  __hip_bfloat16 h = __float2bfloat16(x);
  return __builtin_bit_cast(u16, h);
}
__device__ __forceinline__ float b2f(u16 u) {
  return __bfloat162float(__builtin_bit_cast(__hip_bfloat16, u));
}
__device__ __forceinline__ f32x4 mfma_bf16(bf16x8 a, bf16x8 b, f32x4 c) {
  return __builtin_amdgcn_mfma_f32_16x16x32_bf16(a, b, c, 0, 0, 0);
}
__device__ __forceinline__ void gload_lds16(const u16* gp, u16* lp) {
  __builtin_amdgcn_global_load_lds(
      (const __attribute__((address_space(1))) void*)gp,
      (__attribute__((address_space(3))) void*)lp, 16, 0, 0);
}

// ---------------------------------------------------------------------------
// Kernel 1: fp32 -> bf16 conversion of q,k,v and the 4 weights.
// ---------------------------------------------------------------------------
__global__ __launch_bounds__(256) void k_convert(
    const float* __restrict__ q, const float* __restrict__ k, const float* __restrict__ v,
    const float* __restrict__ wq, const float* __restrict__ wk,
    const float* __restrict__ wv, const float* __restrict__ wo,
    u16* __restrict__ qb, u16* __restrict__ kb, u16* __restrict__ vb,
    u16* __restrict__ wqb, u16* __restrict__ wkb, u16* __restrict__ wvb, u16* __restrict__ wob) {
  int i = (blockIdx.x * 256 + threadIdx.x) * 4;
  const float* src;
  u16* dst;
  int off;
  if (i < 12582912) {              // 3 * 4Mi
    int s = i >> 22;
    off = i - (s << 22);
    src = (s == 0) ? q : ((s == 1) ? k : v);
    dst = (s == 0) ? qb : ((s == 1) ? kb : vb);
  } else {
    int j = i - 12582912;
    int s = j >> 20;
    off = j - (s << 20);
    src = (s == 0) ? wq : ((s == 1) ? wk : ((s == 2) ? wv : wo));
    dst = (s == 0) ? wqb : ((s == 1) ? wkb : ((s == 2) ? wvb : wob));
  }
  float4 f = *(const float4*)(src + off);
  ushort4 o;
  o.x = f2b(f.x); o.y = f2b(f.y); o.z = f2b(f.z); o.w = f2b(f.w);
  *(ushort4*)(dst + off) = o;
}

// ---------------------------------------------------------------------------
// Kernel 2: RoPE cos/sin table, [S][32] each, fp32.
// ---------------------------------------------------------------------------
__global__ __launch_bounds__(256) void k_ropetab(float* __restrict__ cosT, float* __restrict__ sinT) {
  int i = blockIdx.x * 256 + threadIdx.x;   // 0 .. 65536
  int s = i >> 5, j = i & 31;
  float invf = expf(-(float)j * 0.28782313662425574f);  // ln(1e4)/32
  float ang = (float)s * invf;
  float sn, cs;
  sincosf(ang, &sn, &cs);
  cosT[i] = cs;
  sinT[i] = sn;
}

// ---------------------------------------------------------------------------
// Kernel 3: GEMM  C[M,N] = A[M,K] @ W[N,K]^T  (bf16 in, fp32 accum).
// 128x128 tile, BK=32, 4 waves, global_load_lds width=16 staging.
// ---------------------------------------------------------------------------
template <int OUTF>
__global__ __launch_bounds__(256) void k_gemm(
    const u16* __restrict__ A0, const u16* __restrict__ W0, void* __restrict__ O0,
    const u16* __restrict__ A1, const u16* __restrict__ W1, void* __restrict__ O1,
    const u16* __restrict__ A2, const u16* __restrict__ W2, void* __restrict__ O2) {
  const u16* A = (blockIdx.z == 0) ? A0 : ((blockIdx.z == 1) ? A1 : A2);
  const u16* W = (blockIdx.z == 0) ? W0 : ((blockIdx.z == 1) ? W1 : W2);
  void* O = (blockIdx.z == 0) ? O0 : ((blockIdx.z == 1) ? O1 : O2);

  __shared__ u16 As[128 * 32];
  __shared__ u16 Bs[128 * 32];

  const int tid = threadIdx.x;
  const int wave = tid >> 6, lane = tid & 63;
  const int g = lane >> 4, cc = lane & 15;
  const int wm = wave >> 1, wn = wave & 1;
  const int row0 = blockIdx.x * 128, col0 = blockIdx.y * 128;

  const int srow = wave * 16 + (lane >> 2);
  const int sseg = (lane & 3) * 8;
  const u16* Ap  = A + (size_t)(row0 + srow) * 1024 + sseg;
  const u16* Ap2 = Ap + 64 * 1024;
  const u16* Wp  = W + (size_t)(col0 + srow) * 1024 + sseg;
  const u16* Wp2 = Wp + 64 * 1024;
  u16* asl  = &As[wave * 512];
  u16* asl2 = &As[2048 + wave * 512];
  u16* bsl  = &Bs[wave * 512];
  u16* bsl2 = &Bs[2048 + wave * 512];

  f32x4 acc[4][4] = {};

  for (int k0 = 0; k0 < 1024; k0 += 32) {
    __syncthreads();
    gload_lds16(Ap + k0, asl);
    gload_lds16(Ap2 + k0, asl2);
    gload_lds16(Wp + k0, bsl);
    gload_lds16(Wp2 + k0, bsl2);
    __syncthreads();
    bf16x8 af[4], bfv[4];
#pragma unroll
    for (int mi = 0; mi < 4; ++mi)
      af[mi] = *(const bf16x8*)&As[(wm * 64 + mi * 16 + cc) * 32 + g * 8];
#pragma unroll
    for (int ni = 0; ni < 4; ++ni)
      bfv[ni] = *(const bf16x8*)&Bs[(wn * 64 + ni * 16 + cc) * 32 + g * 8];
#pragma unroll
    for (int mi = 0; mi < 4; ++mi)
#pragma unroll
      for (int ni = 0; ni < 4; ++ni)
        acc[mi][ni] = mfma_bf16(af[mi], bfv[ni], acc[mi][ni]);
  }

#pragma unroll
  for (int mi = 0; mi < 4; ++mi)
#pragma unroll
    for (int ni = 0; ni < 4; ++ni)
#pragma unroll
      for (int r = 0; r < 4; ++r) {
        const int row = row0 + wm * 64 + mi * 16 + g * 4 + r;
        const int col = col0 + wn * 64 + ni * 16 + cc;
        const float vv = acc[mi][ni][r];
        if (OUTF)
          ((float*)O)[row * 1024 + col] = vv;
        else
          ((u16*)O)[row * 1024 + col] = f2b(vv);
      }
}

// ---------------------------------------------------------------------------
// Kernel 4: RoPE + [B,S,H,DK]->[B,H,S,DK] relayout. Q scaled by
// (1/8)*log2(e) so attention softmax can run in exp2 domain.
// ---------------------------------------------------------------------------
__global__ __launch_bounds__(256) void k_rope(
    const u16* __restrict__ tq, const u16* __restrict__ tk,
    const float* __restrict__ cosT, const float* __restrict__ sinT,
    u16* __restrict__ Qr, u16* __restrict__ Kr) {
  int idx = blockIdx.x * 256 + threadIdx.x;  // 0 .. 4Mi
  int t = idx >> 21;
  int r = idx & ((1 << 21) - 1);
  int j = r & 31;
  int h = (r >> 5) & 15;
  int s = (r >> 9) & 2047;
  int b = (r >> 20) & 1;

  const u16* in = t ? tk : tq;
  u16* out = t ? Kr : Qr;

  int bi = (b * Sdim + s) * Ddim + h * 64 + j;
  float x1 = b2f(in[bi]);
  float x2 = b2f(in[bi + 32]);
  float cv = cosT[s * 32 + j];
  float sv = sinT[s * 32 + j];
  float o1 = x1 * cv - x2 * sv;
  float o2 = x2 * cv + x1 * sv;
  if (t == 0) { o1 *= 0.18033688011112042f; o2 *= 0.18033688011112042f; } // 0.125*log2e
  int bo = ((b * Hdim + h) * Sdim + s) * 64 + j;
  out[bo] = f2b(o1);
  out[bo + 32] = f2b(o2);
}

// ---------------------------------------------------------------------------
// Kernel 5: V relayout+transpose: tmpV [B,S,H*DK] -> Vt [BH, DK, S] with keys
// permuted within each 32-chunk into MFMA kappa-order: pos = (kap&15)>>2 *8
// + (kap>>4)*4 + (kap&3), so an attention lane reads its 8 keys as one b128.
// ---------------------------------------------------------------------------
__global__ __launch_bounds__(256) void k_transv(const u16* __restrict__ tv, u16* __restrict__ Vt) {
  __shared__ u16 tl[64][72];
  const int bh = blockIdx.y;
  const int b = bh >> 4, h = bh & 15;
  const int s0 = blockIdx.x * 64;
  const int tid = threadIdx.x;
#pragma unroll
  for (int p = 0; p < 4; ++p) {
    int row = p * 16 + (tid >> 4);
    int dc = (tid & 15) * 4;
    ushort4 val = *(const ushort4*)(tv + (b * Sdim + s0 + row) * Ddim + h * 64 + dc);
    *(ushort4*)&tl[row][dc] = val;
  }
  __syncthreads();
#pragma unroll
  for (int p = 0; p < 4; ++p) {
    int dr = p * 16 + (tid >> 4);
    int sc = (tid & 15) * 4;
    ushort4 o;
    o.x = tl[sc + 0][dr];
    o.y = tl[sc + 1][dr];
    o.z = tl[sc + 2][dr];
    o.w = tl[sc + 3][dr];
    int s_abs = s0 + sc;
    int cch = s_abs >> 5;
    int kap = s_abs & 31;
    int g2 = (kap >> 2) & 3;
    int seg = kap >> 4;
    *(ushort4*)(Vt + (size_t)(bh * 64 + dr) * Sdim + (cch << 5) + (g2 << 3) + (seg << 2)) = o;
  }
}

// ---------------------------------------------------------------------------
// Kernel 6: causal flash attention, LDS-staged 64-key chunks, 2-phase
// pipeline. Block = 4 waves = 128 q-rows of one (b,h); wave owns 32 rows
// (two 16-row tiles). Per chunk: 16KB stage (K 8KB + V 8KB) via 4
// global_load_lds per wave, double-buffered; barrier -> issue stage t+1 ->
// compute t (two independent 32-key sub-streams for ILP). LDS granule
// swizzle: granule ^= (row&7), via pre-swizzled global source (T21).
// Softmax: swapped-operand in-register, exp2 domain, defer-max THR=11.5.
// Diagonal chunk modes: even wave (TRI, SKIP), odd wave (FULL, TRI).
// ---------------------------------------------------------------------------
template <int M0, int M1>   // per 32-key half: 0=full, 1=tri(diag), 2=skip
__device__ __forceinline__ void attn_chunk64(
    const u16* __restrict__ kl, const u16* __restrict__ vl, int cc, int g,
    const bf16x8 qf[4],
    float& mold0, float& mold1, float& lsum0, float& lsum1,
    f32x4 ot0[4], f32x4 ot1[4]) {
  const int m7 = cc & 7;
  const int gA = (g ^ m7) * 8;
  const int gB = ((g + 4) ^ m7) * 8;

  // QK, sub-chunk 0 (keys 0..31 of chunk)
  f32x4 x0A0 = {}, x0B0 = {}, x0A1 = {}, x0B1 = {};
  {
    const u16* r0 = kl + cc * 64;
    const u16* r1 = kl + (16 + cc) * 64;
    bf16x8 k0 = *(const bf16x8*)(r0 + gA);
    bf16x8 k1 = *(const bf16x8*)(r0 + gB);
    bf16x8 k2 = *(const bf16x8*)(r1 + gA);
    bf16x8 k3 = *(const bf16x8*)(r1 + gB);
    x0A0 = mfma_bf16(k0, qf[0], x0A0);
    x0A0 = mfma_bf16(k1, qf[1], x0A0);
    x0B0 = mfma_bf16(k2, qf[0], x0B0);
    x0B0 = mfma_bf16(k3, qf[1], x0B0);
    x0A1 = mfma_bf16(k0, qf[2], x0A1);
    x0A1 = mfma_bf16(k1, qf[3], x0A1);
    x0B1 = mfma_bf16(k2, qf[2], x0B1);
    x0B1 = mfma_bf16(k3, qf[3], x0B1);
  }
  // QK, sub-chunk 1 (keys 32..63)
  f32x4 x1A0 = {}, x1B0 = {}, x1A1 = {}, x1B1 = {};
  if (M1 != 2) {
    const u16* r0 = kl + (32 + cc) * 64;
    const u16* r1 = kl + (48 + cc) * 64;
    bf16x8 k0 = *(const bf16x8*)(r0 + gA);
    bf16x8 k1 = *(const bf16x8*)(r0 + gB);
    bf16x8 k2 = *(const bf16x8*)(r1 + gA);
    bf16x8 k3 = *(const bf16x8*)(r1 + gB);
    x1A0 = mfma_bf16(k0, qf[0], x1A0);
    x1A0 = mfma_bf16(k1, qf[1], x1A0);
    x1B0 = mfma_bf16(k2, qf[0], x1B0);
    x1B0 = mfma_bf16(k3, qf[1], x1B0);
    x1A1 = mfma_bf16(k0, qf[2], x1A1);
    x1A1 = mfma_bf16(k1, qf[3], x1A1);
    x1B1 = mfma_bf16(k2, qf[2], x1B1);
    x1B1 = mfma_bf16(k3, qf[3], x1B1);
  }

  float p0[16], p1[16];
#pragma unroll
  for (int r = 0; r < 4; ++r) {
    const int ka = g * 4 + r;
    float a0 = x0A0[r], b0 = x0B0[r], a1 = x0A1[r], b1 = x0B1[r];
    if (M0 == 1) {
      a0 = (ka <= cc) ? a0 : -30000.0f;
      b0 = -30000.0f;
      b1 = (ka <= cc) ? b1 : -30000.0f;
    }
    p0[r] = a0; p0[4 + r] = b0;
    p1[r] = a1; p1[4 + r] = b1;
  }
  if (M1 != 2) {
#pragma unroll
    for (int r = 0; r < 4; ++r) {
      const int ka = g * 4 + r;
      float a0 = x1A0[r], b0 = x1B0[r], a1 = x1A1[r], b1 = x1B1[r];
      if (M1 == 1) {
        a0 = (ka <= cc) ? a0 : -30000.0f;
        b0 = -30000.0f;
        b1 = (ka <= cc) ? b1 : -30000.0f;
      }
      p0[8 + r] = a0; p0[12 + r] = b0;
      p1[8 + r] = a1; p1[12 + r] = b1;
    }
  }
  const int NP = (M1 == 2) ? 8 : 16;
  float m0 = p0[0], m1 = p1[0];
#pragma unroll
  for (int j = 1; j < 16; ++j)
    if (j < NP) { m0 = fmaxf(m0, p0[j]); m1 = fmaxf(m1, p1[j]); }
  m0 = fmaxf(m0, __shfl_xor(m0, 16));
  m0 = fmaxf(m0, __shfl_xor(m0, 32));
  m1 = fmaxf(m1, __shfl_xor(m1, 16));
  m1 = fmaxf(m1, __shfl_xor(m1, 32));

  if (!__all((m0 <= mold0 + 11.5f) && (m1 <= mold1 + 11.5f))) {
    const float mn0 = fmaxf(mold0, m0), mn1 = fmaxf(mold1, m1);
    const float al0 = exp2f(mold0 - mn0), al1 = exp2f(mold1 - mn1);
    mold0 = mn0; mold1 = mn1;
    lsum0 *= al0; lsum1 *= al1;
#pragma unroll
    for (int dc = 0; dc < 4; ++dc) { ot0[dc] *= al0; ot1[dc] *= al1; }
  }

  float rs0 = 0.f, rs1 = 0.f;
  union { bf16x8 v; u16 s[8]; } a0u, a1u, b0u, b1u;
#pragma unroll
  for (int j = 0; j < 8; ++j) {
    float e0 = exp2f(p0[j] - mold0);
    float e1 = exp2f(p1[j] - mold1);
    rs0 += e0; rs1 += e1;
    a0u.s[j] = f2b(e0);
    a1u.s[j] = f2b(e1);
  }
  if (M1 != 2) {
#pragma unroll
    for (int j = 0; j < 8; ++j) {
      float e0 = exp2f(p0[8 + j] - mold0);
      float e1 = exp2f(p1[8 + j] - mold1);
      rs0 += e0; rs1 += e1;
      b0u.s[j] = f2b(e0);
      b1u.s[j] = f2b(e1);
    }
  }
  lsum0 += rs0; lsum1 += rs1;

#pragma unroll
  for (int dc = 0; dc < 4; ++dc) {
    bf16x8 vv = *(const bf16x8*)(vl + (dc * 16 + cc) * 64 + gA);
    ot0[dc] = mfma_bf16(vv, a0u.v, ot0[dc]);
    ot1[dc] = mfma_bf16(vv, a1u.v, ot1[dc]);
  }
  if (M1 != 2) {
#pragma unroll
    for (int dc = 0; dc < 4; ++dc) {
      bf16x8 vv = *(const bf16x8*)(vl + (dc * 16 + cc) * 64 + gB);
      ot0[dc] = mfma_bf16(vv, b0u.v, ot0[dc]);
      ot1[dc] = mfma_bf16(vv, b1u.v, ot1[dc]);
    }
  }
}

__global__ __launch_bounds__(256, 2) void k_attn(
    const u16* __restrict__ Qr, const u16* __restrict__ Kr,
    const u16* __restrict__ Vt, u16* __restrict__ Oc) {
  __shared__ u16 Kl[2][4096];   // [buf][64 keys x 64 d], granule-swizzled
  __shared__ u16 Vl[2][4096];   // [buf][64 d x 64 keys], granule-swizzled

  const int x = blockIdx.x;          // 0..511
  const int bh = x & 31;
  const int t5 = x >> 5;             // 0..15
  const int i = (t5 < 8) ? (15 - 2 * t5) : (2 * (t5 - 8));  // q-block of 128 rows
  const int b = bh >> 4, h = bh & 15;
  const int tid = threadIdx.x;
  const int w = tid >> 6;
  const int lane = tid & 63;
  const int g = lane >> 4, cc = lane & 15;

  const int qrow0 = i * 128 + w * 32;
  const int myDiag = 2 * i + (w >> 1);   // wave's diagonal 64-chunk
  const int NC = 2 * i + 2;              // 64-chunks staged by this block

  const u16* Kp = Kr + (size_t)bh * (Sdim * 64);
  const u16* Vp = Vt + (size_t)bh * (64 * Sdim);
  const u16* Qp = Qr + (size_t)(bh * Sdim + qrow0) * 64;

  // staging sources (pre-swizzled, T21): instr covers 8 rows x 128B; lane:
  // row_local = lane>>3, granule = lane&7, src granule = granule ^ row_local.
  const int rloc = lane >> 3;
  const int sg = (lane & 7) ^ rloc;
  const u16* kS = Kp + (size_t)(w * 16 + rloc) * 64 + sg * 8;
  const u16* vS = Vp + (size_t)(w * 16 + rloc) * 2048 + sg * 8;

  bf16x8 qf[4];
  qf[0] = *(const bf16x8*)(Qp + cc * 64 + g * 8);
  qf[1] = *(const bf16x8*)(Qp + cc * 64 + g * 8 + 32);
  qf[2] = *(const bf16x8*)(Qp + (16 + cc) * 64 + g * 8);
  qf[3] = *(const bf16x8*)(Qp + (16 + cc) * 64 + g * 8 + 32);

  float mold0 = -1e30f, mold1 = -1e30f, lsum0 = 0.f, lsum1 = 0.f;
  f32x4 ot0[4] = {}, ot1[4] = {};

  // prologue: stage chunk 0 into buf 0 (4 instrs per wave: 2 K + 2 V)
  gload_lds16(kS, &Kl[0][w * 1024]);
  gload_lds16(kS + 512, &Kl[0][w * 1024 + 512]);
  gload_lds16(vS, &Vl[0][w * 1024]);
  gload_lds16(vS + 16384, &Vl[0][w * 1024 + 512]);

  for (int t = 0; t < NC; ++t) {
    __syncthreads();                 // drains stage(t)
    if (t + 1 < NC) {                // issue stage(t+1); hidden by compute(t)
      const int nb = (t + 1) & 1;
      const size_t ko = (size_t)(t + 1) * 4096;
      const size_t vo = (size_t)(t + 1) * 64;
      gload_lds16(kS + ko, &Kl[nb][w * 1024]);
      gload_lds16(kS + ko + 512, &Kl[nb][w * 1024 + 512]);
      gload_lds16(vS + vo, &Vl[nb][w * 1024]);
      gload_lds16(vS + vo + 16384, &Vl[nb][w * 1024 + 512]);
    }
    if (t <= myDiag) {
      const u16* kl = &Kl[t & 1][0];
      const u16* vl = &Vl[t & 1][0];
      if (t < myDiag)
        attn_chunk64<0, 0>(kl, vl, cc, g, qf, mold0, mold1, lsum0, lsum1, ot0, ot1);
      else if (w & 1)
        attn_chunk64<0, 1>(kl, vl, cc, g, qf, mold0, mold1, lsum0, lsum1, ot0, ot1);
      else
        attn_chunk64<1, 2>(kl, vl, cc, g, qf, mold0, mold1, lsum0, lsum1, ot0, ot1);
    }
  }

  lsum0 += __shfl_xor(lsum0, 16);
  lsum0 += __shfl_xor(lsum0, 32);
  lsum1 += __shfl_xor(lsum1, 16);
  lsum1 += __shfl_xor(lsum1, 32);
  const float rl0 = 1.0f / lsum0, rl1 = 1.0f / lsum1;

  u16* dst0 = Oc + (size_t)(b * Sdim + qrow0 + cc) * Ddim + h * 64 + g * 4;
  u16* dst1 = dst0 + 16 * Ddim;
#pragma unroll
  for (int dc = 0; dc < 4; ++dc) {
    ushort4 o0, o1;
    o0.x = f2b(ot0[dc][0] * rl0);
    o0.y = f2b(ot0[dc][1] * rl0);
    o0.z = f2b(ot0[dc][2] * rl0);
    o0.w = f2b(ot0[dc][3] * rl0);
    o1.x = f2b(ot1[dc][0] * rl1);
    o1.y = f2b(ot1[dc][1] * rl1);
    o1.z = f2b(ot1[dc][2] * rl1);
    o1.w = f2b(ot1[dc][3] * rl1);
    *(ushort4*)(dst0 + dc * 16) = o0;
    *(ushort4*)(dst1 + dc * 16) = o1;
  }
}

// ---------------------------------------------------------------------------
extern "C" void kernel_launch(void* const* d_in, const int* in_sizes, int n_in,
                              void* d_out, int out_size, void* d_ws, size_t ws_size,
                              hipStream_t stream) {
  const float* q = (const float*)d_in[0];
  const float* k = (const float*)d_in[1];
  const float* v = (const float*)d_in[2];
  const float* wq = (const float*)d_in[3];
  const float* wk = (const float*)d_in[4];
  const float* wv = (const float*)d_in[5];
  const float* wo = (const float*)d_in[6];
  float* out = (float*)d_out;

  uint8_t* ws = (uint8_t*)d_ws;
  const size_t MiB = 1ull << 20;
  u16* qb  = (u16*)(ws + 0 * MiB);
  u16* kb  = (u16*)(ws + 8 * MiB);
  u16* vb  = (u16*)(ws + 16 * MiB);
  u16* wqb = (u16*)(ws + 24 * MiB);
  u16* wkb = (u16*)(ws + 26 * MiB);
  u16* wvb = (u16*)(ws + 28 * MiB);
  u16* wob = (u16*)(ws + 30 * MiB);
  u16* tQ  = (u16*)(ws + 32 * MiB);
  u16* tK  = (u16*)(ws + 40 * MiB);
  u16* tV  = (u16*)(ws + 48 * MiB);
  u16* Qr  = (u16*)(ws + 56 * MiB);
  u16* Kr  = (u16*)(ws + 64 * MiB);
  u16* Vt  = (u16*)(ws + 72 * MiB);
  u16* Oc  = (u16*)(ws + 80 * MiB);
  float* cosT = (float*)(ws + 88 * MiB);
  float* sinT = (float*)(ws + 88 * MiB + 256 * 1024);

  k_convert<<<16384, 256, 0, stream>>>(q, k, v, wq, wk, wv, wo,
                                       qb, kb, vb, wqb, wkb, wvb, wob);
  k_ropetab<<<256, 256, 0, stream>>>(cosT, sinT);
  k_gemm<0><<<dim3(32, 8, 3), 256, 0, stream>>>(qb, wqb, tQ, kb, wkb, tK, vb, wvb, tV);
  k_rope<<<16384, 256, 0, stream>>>(tQ, tK, cosT, sinT, Qr, Kr);
  k_transv<<<dim3(32, 32), 256, 0, stream>>>(tV, Vt);
  k_attn<<<512, 256, 0, stream>>>(Qr, Kr, Vt, Oc);
  k_gemm<1><<<dim3(32, 8, 1), 256, 0, stream>>>(Oc, wob, out, Oc, wob, out, Oc, wob, out);
}

// Round 6
// 134.697 us; speedup vs baseline: 2.3439x; 1.1112x over previous
//
#include <hip/hip_runtime.h>
#include <hip/hip_bf16.h>
#include <stdint.h>

#define Bdim 2
#define Sdim 2048
#define Ddim 1024
#define Hdim 16
// DK = 64, BH = 32, M = B*S = 4096

typedef unsigned short u16;
typedef __bf16 bf16x8 __attribute__((ext_vector_type(8)));
typedef float f32x4 __attribute__((ext_vector_type(4)));

__device__ __forceinline__ u16 f2b(float x) {
  return __builtin_bit_cast(u16, (__bf16)x);
}
__device__ __forceinline__ float b2f(u16 u) {
  return __bfloat162float(__builtin_bit_cast(__hip_bfloat16, u));
}
__device__ __forceinline__ f32x4 mfma_bf16(bf16x8 a, bf16x8 b, f32x4 c) {
  return __builtin_amdgcn_mfma_f32_16x16x32_bf16(a, b, c, 0, 0, 0);
}
__device__ __forceinline__ void gload_lds16(const u16* gp, u16* lp) {
  __builtin_amdgcn_global_load_lds(
      (const __attribute__((address_space(1))) void*)gp,
      (__attribute__((address_space(3))) void*)lp, 16, 0, 0);
}

// ---------------------------------------------------------------------------
// Kernel 1: fp32 -> bf16 conversion of q,k,v and the 4 weights.
// ---------------------------------------------------------------------------
__global__ __launch_bounds__(256) void k_convert(
    const float* __restrict__ q, const float* __restrict__ k, const float* __restrict__ v,
    const float* __restrict__ wq, const float* __restrict__ wk,
    const float* __restrict__ wv, const float* __restrict__ wo,
    u16* __restrict__ qb, u16* __restrict__ kb, u16* __restrict__ vb,
    u16* __restrict__ wqb, u16* __restrict__ wkb, u16* __restrict__ wvb, u16* __restrict__ wob) {
  int i = (blockIdx.x * 256 + threadIdx.x) * 4;
  const float* src;
  u16* dst;
  int off;
  if (i < 12582912) {              // 3 * 4Mi
    int s = i >> 22;
    off = i - (s << 22);
    src = (s == 0) ? q : ((s == 1) ? k : v);
    dst = (s == 0) ? qb : ((s == 1) ? kb : vb);
  } else {
    int j = i - 12582912;
    int s = j >> 20;
    off = j - (s << 20);
    src = (s == 0) ? wq : ((s == 1) ? wk : ((s == 2) ? wv : wo));
    dst = (s == 0) ? wqb : ((s == 1) ? wkb : ((s == 2) ? wvb : wob));
  }
  float4 f = *(const float4*)(src + off);
  ushort4 o;
  o.x = f2b(f.x); o.y = f2b(f.y); o.z = f2b(f.z); o.w = f2b(f.w);
  *(ushort4*)(dst + off) = o;
}

// ---------------------------------------------------------------------------
// Kernel 2: RoPE cos/sin table, [S][32] each, fp32.
// ---------------------------------------------------------------------------
__global__ __launch_bounds__(256) void k_ropetab(float* __restrict__ cosT, float* __restrict__ sinT) {
  int i = blockIdx.x * 256 + threadIdx.x;   // 0 .. 65536
  int s = i >> 5, j = i & 31;
  float invf = expf(-(float)j * 0.28782313662425574f);  // ln(1e4)/32
  float ang = (float)s * invf;
  float sn, cs;
  sincosf(ang, &sn, &cs);
  cosT[i] = cs;
  sinT[i] = sn;
}

// ---------------------------------------------------------------------------
// Kernel 3: GEMM  C[M,N] = A[M,K] @ W[N,K]^T  (bf16 in, fp32 accum).
// 128x128 tile, BK=32, 4 waves, global_load_lds width=16 staging.
// ---------------------------------------------------------------------------
template <int OUTF>
__global__ __launch_bounds__(256) void k_gemm(
    const u16* __restrict__ A0, const u16* __restrict__ W0, void* __restrict__ O0,
    const u16* __restrict__ A1, const u16* __restrict__ W1, void* __restrict__ O1,
    const u16* __restrict__ A2, const u16* __restrict__ W2, void* __restrict__ O2) {
  const u16* A = (blockIdx.z == 0) ? A0 : ((blockIdx.z == 1) ? A1 : A2);
  const u16* W = (blockIdx.z == 0) ? W0 : ((blockIdx.z == 1) ? W1 : W2);
  void* O = (blockIdx.z == 0) ? O0 : ((blockIdx.z == 1) ? O1 : O2);

  __shared__ u16 As[128 * 32];
  __shared__ u16 Bs[128 * 32];

  const int tid = threadIdx.x;
  const int wave = tid >> 6, lane = tid & 63;
  const int g = lane >> 4, cc = lane & 15;
  const int wm = wave >> 1, wn = wave & 1;
  const int row0 = blockIdx.x * 128, col0 = blockIdx.y * 128;

  const int srow = wave * 16 + (lane >> 2);
  const int sseg = (lane & 3) * 8;
  const u16* Ap  = A + (size_t)(row0 + srow) * 1024 + sseg;
  const u16* Ap2 = Ap + 64 * 1024;
  const u16* Wp  = W + (size_t)(col0 + srow) * 1024 + sseg;
  const u16* Wp2 = Wp + 64 * 1024;
  u16* asl  = &As[wave * 512];
  u16* asl2 = &As[2048 + wave * 512];
  u16* bsl  = &Bs[wave * 512];
  u16* bsl2 = &Bs[2048 + wave * 512];

  f32x4 acc[4][4] = {};

  for (int k0 = 0; k0 < 1024; k0 += 32) {
    __syncthreads();
    gload_lds16(Ap + k0, asl);
    gload_lds16(Ap2 + k0, asl2);
    gload_lds16(Wp + k0, bsl);
    gload_lds16(Wp2 + k0, bsl2);
    __syncthreads();
    bf16x8 af[4], bfv[4];
#pragma unroll
    for (int mi = 0; mi < 4; ++mi)
      af[mi] = *(const bf16x8*)&As[(wm * 64 + mi * 16 + cc) * 32 + g * 8];
#pragma unroll
    for (int ni = 0; ni < 4; ++ni)
      bfv[ni] = *(const bf16x8*)&Bs[(wn * 64 + ni * 16 + cc) * 32 + g * 8];
#pragma unroll
    for (int mi = 0; mi < 4; ++mi)
#pragma unroll
      for (int ni = 0; ni < 4; ++ni)
        acc[mi][ni] = mfma_bf16(af[mi], bfv[ni], acc[mi][ni]);
  }

#pragma unroll
  for (int mi = 0; mi < 4; ++mi)
#pragma unroll
    for (int ni = 0; ni < 4; ++ni)
#pragma unroll
      for (int r = 0; r < 4; ++r) {
        const int row = row0 + wm * 64 + mi * 16 + g * 4 + r;
        const int col = col0 + wn * 64 + ni * 16 + cc;
        const float vv = acc[mi][ni][r];
        if (OUTF)
          ((float*)O)[row * 1024 + col] = vv;
        else
          ((u16*)O)[row * 1024 + col] = f2b(vv);
      }
}

// ---------------------------------------------------------------------------
// Kernel 4: RoPE + [B,S,H,DK]->[B,H,S,DK] relayout. Q scaled by
// (1/8)*log2(e) so attention softmax can run in exp2 domain.
// ---------------------------------------------------------------------------
__global__ __launch_bounds__(256) void k_rope(
    const u16* __restrict__ tq, const u16* __restrict__ tk,
    const float* __restrict__ cosT, const float* __restrict__ sinT,
    u16* __restrict__ Qr, u16* __restrict__ Kr) {
  int idx = blockIdx.x * 256 + threadIdx.x;  // 0 .. 4Mi
  int t = idx >> 21;
  int r = idx & ((1 << 21) - 1);
  int j = r & 31;
  int h = (r >> 5) & 15;
  int s = (r >> 9) & 2047;
  int b = (r >> 20) & 1;

  const u16* in = t ? tk : tq;
  u16* out = t ? Kr : Qr;

  int bi = (b * Sdim + s) * Ddim + h * 64 + j;
  float x1 = b2f(in[bi]);
  float x2 = b2f(in[bi + 32]);
  float cv = cosT[s * 32 + j];
  float sv = sinT[s * 32 + j];
  float o1 = x1 * cv - x2 * sv;
  float o2 = x2 * cv + x1 * sv;
  if (t == 0) { o1 *= 0.18033688011112042f; o2 *= 0.18033688011112042f; } // 0.125*log2e
  int bo = ((b * Hdim + h) * Sdim + s) * 64 + j;
  out[bo] = f2b(o1);
  out[bo + 32] = f2b(o2);
}

// ---------------------------------------------------------------------------
// Kernel 5: V relayout+transpose: tmpV [B,S,H*DK] -> Vt [BH, DK, S] with keys
// permuted within each 32-chunk into MFMA kappa-order: pos = (kap&15)>>2 *8
// + (kap>>4)*4 + (kap&3), so an attention lane reads its 8 keys as one b128.
// ---------------------------------------------------------------------------
__global__ __launch_bounds__(256) void k_transv(const u16* __restrict__ tv, u16* __restrict__ Vt) {
  __shared__ u16 tl[64][72];
  const int bh = blockIdx.y;
  const int b = bh >> 4, h = bh & 15;
  const int s0 = blockIdx.x * 64;
  const int tid = threadIdx.x;
#pragma unroll
  for (int p = 0; p < 4; ++p) {
    int row = p * 16 + (tid >> 4);
    int dc = (tid & 15) * 4;
    ushort4 val = *(const ushort4*)(tv + (b * Sdim + s0 + row) * Ddim + h * 64 + dc);
    *(ushort4*)&tl[row][dc] = val;
  }
  __syncthreads();
#pragma unroll
  for (int p = 0; p < 4; ++p) {
    int dr = p * 16 + (tid >> 4);
    int sc = (tid & 15) * 4;
    ushort4 o;
    o.x = tl[sc + 0][dr];
    o.y = tl[sc + 1][dr];
    o.z = tl[sc + 2][dr];
    o.w = tl[sc + 3][dr];
    int s_abs = s0 + sc;
    int cch = s_abs >> 5;
    int kap = s_abs & 31;
    int g2 = (kap >> 2) & 3;
    int seg = kap >> 4;
    *(ushort4*)(Vt + (size_t)(bh * 64 + dr) * Sdim + (cch << 5) + (g2 << 3) + (seg << 2)) = o;
  }
}

// ---------------------------------------------------------------------------
// Kernel 6: causal flash attention, equal-work split-K decomposition.
// 512 blocks (bh 0..31 x 16 slots), ALL blocks 16-18 chunk-units -> sustained
// 2 waves/SIMD. Per head: pair (iH=15-p heavy, iL=p light). half0 block:
// heavy chunks [0,18) (branch-free full chunks; final if iH==8 else partial
// piece 0). half1 block: heavy chunks [18,nH) incl diagonal (partial piece 1)
// then full light tile (final). Partials {O f32, m, l} merged by k_comb.
// Defer-max is SHUFFLE-FREE in the hot path: mold stays row-uniform, so each
// lane tests its private 8-key max; cross-lane max only in the rare rescale.
// ---------------------------------------------------------------------------
template <int M0, int M1>   // per 32-key half: 0=full, 1=tri(diag), 2=skip
__device__ __forceinline__ void attn_chunk64(
    const u16* __restrict__ kl, const u16* __restrict__ vl, int cc, int g,
    const bf16x8 qf[4],
    float& mold0, float& mold1, float& lsum0, float& lsum1,
    f32x4 ot0[4], f32x4 ot1[4]) {
  const int m7 = cc & 7;
  const int gA = (g ^ m7) * 8;
  const int gB = ((g + 4) ^ m7) * 8;

  f32x4 x0A0 = {}, x0B0 = {}, x0A1 = {}, x0B1 = {};
  {
    const u16* r0 = kl + cc * 64;
    const u16* r1 = kl + (16 + cc) * 64;
    bf16x8 k0 = *(const bf16x8*)(r0 + gA);
    bf16x8 k1 = *(const bf16x8*)(r0 + gB);
    bf16x8 k2 = *(const bf16x8*)(r1 + gA);
    bf16x8 k3 = *(const bf16x8*)(r1 + gB);
    x0A0 = mfma_bf16(k0, qf[0], x0A0);
    x0A0 = mfma_bf16(k1, qf[1], x0A0);
    x0B0 = mfma_bf16(k2, qf[0], x0B0);
    x0B0 = mfma_bf16(k3, qf[1], x0B0);
    x0A1 = mfma_bf16(k0, qf[2], x0A1);
    x0A1 = mfma_bf16(k1, qf[3], x0A1);
    x0B1 = mfma_bf16(k2, qf[2], x0B1);
    x0B1 = mfma_bf16(k3, qf[3], x0B1);
  }
  f32x4 x1A0 = {}, x1B0 = {}, x1A1 = {}, x1B1 = {};
  if (M1 != 2) {
    const u16* r0 = kl + (32 + cc) * 64;
    const u16* r1 = kl + (48 + cc) * 64;
    bf16x8 k0 = *(const bf16x8*)(r0 + gA);
    bf16x8 k1 = *(const bf16x8*)(r0 + gB);
    bf16x8 k2 = *(const bf16x8*)(r1 + gA);
    bf16x8 k3 = *(const bf16x8*)(r1 + gB);
    x1A0 = mfma_bf16(k0, qf[0], x1A0);
    x1A0 = mfma_bf16(k1, qf[1], x1A0);
    x1B0 = mfma_bf16(k2, qf[0], x1B0);
    x1B0 = mfma_bf16(k3, qf[1], x1B0);
    x1A1 = mfma_bf16(k0, qf[2], x1A1);
    x1A1 = mfma_bf16(k1, qf[3], x1A1);
    x1B1 = mfma_bf16(k2, qf[2], x1B1);
    x1B1 = mfma_bf16(k3, qf[3], x1B1);
  }

  float p0[16], p1[16];
#pragma unroll
  for (int r = 0; r < 4; ++r) {
    const int ka = g * 4 + r;
    float a0 = x0A0[r], b0 = x0B0[r], a1 = x0A1[r], b1 = x0B1[r];
    if (M0 == 1) {
      a0 = (ka <= cc) ? a0 : -30000.0f;
      b0 = -30000.0f;
      b1 = (ka <= cc) ? b1 : -30000.0f;
    }
    p0[r] = a0; p0[4 + r] = b0;
    p1[r] = a1; p1[4 + r] = b1;
  }
  if (M1 != 2) {
#pragma unroll
    for (int r = 0; r < 4; ++r) {
      const int ka = g * 4 + r;
      float a0 = x1A0[r], b0 = x1B0[r], a1 = x1A1[r], b1 = x1B1[r];
      if (M1 == 1) {
        a0 = (ka <= cc) ? a0 : -30000.0f;
        b0 = -30000.0f;
        b1 = (ka <= cc) ? b1 : -30000.0f;
      }
      p0[8 + r] = a0; p0[12 + r] = b0;
      p1[8 + r] = a1; p1[12 + r] = b1;
    }
  }
  const int NP = (M1 == 2) ? 8 : 16;
  float m0 = p0[0], m1 = p1[0];
#pragma unroll
  for (int j = 1; j < 16; ++j)
    if (j < NP) { m0 = fmaxf(m0, p0[j]); m1 = fmaxf(m1, p1[j]); }

  // shuffle-free defer test (mold is row-uniform by construction)
  if (!__all((m0 <= mold0 + 11.5f) && (m1 <= mold1 + 11.5f))) {
    float M0v = fmaxf(m0, __shfl_xor(m0, 16));
    M0v = fmaxf(M0v, __shfl_xor(M0v, 32));
    float M1v = fmaxf(m1, __shfl_xor(m1, 16));
    M1v = fmaxf(M1v, __shfl_xor(M1v, 32));
    M0v = fmaxf(mold0, M0v);
    M1v = fmaxf(mold1, M1v);
    const float al0 = exp2f(mold0 - M0v), al1 = exp2f(mold1 - M1v);
    mold0 = M0v; mold1 = M1v;
    lsum0 *= al0; lsum1 *= al1;
#pragma unroll
    for (int dc = 0; dc < 4; ++dc) { ot0[dc] *= al0; ot1[dc] *= al1; }
  }

  float rs0 = 0.f, rs1 = 0.f;
  bf16x8 a0v, a1v, b0v2, b1v2;
#pragma unroll
  for (int j = 0; j < 8; ++j) {
    float e0 = exp2f(p0[j] - mold0);
    float e1 = exp2f(p1[j] - mold1);
    rs0 += e0; rs1 += e1;
    a0v[j] = (__bf16)e0;
    a1v[j] = (__bf16)e1;
  }
  if (M1 != 2) {
#pragma unroll
    for (int j = 0; j < 8; ++j) {
      float e0 = exp2f(p0[8 + j] - mold0);
      float e1 = exp2f(p1[8 + j] - mold1);
      rs0 += e0; rs1 += e1;
      b0v2[j] = (__bf16)e0;
      b1v2[j] = (__bf16)e1;
    }
  }
  lsum0 += rs0; lsum1 += rs1;

#pragma unroll
  for (int dc = 0; dc < 4; ++dc) {
    bf16x8 vv = *(const bf16x8*)(vl + (dc * 16 + cc) * 64 + gA);
    ot0[dc] = mfma_bf16(vv, a0v, ot0[dc]);
    ot1[dc] = mfma_bf16(vv, a1v, ot1[dc]);
  }
  if (M1 != 2) {
#pragma unroll
    for (int dc = 0; dc < 4; ++dc) {
      bf16x8 vv = *(const bf16x8*)(vl + (dc * 16 + cc) * 64 + gB);
      ot0[dc] = mfma_bf16(vv, b0v2, ot0[dc]);
      ot1[dc] = mfma_bf16(vv, b1v2, ot1[dc]);
    }
  }
}

__global__ __launch_bounds__(256, 2) void k_attn(
    const u16* __restrict__ Qr, const u16* __restrict__ Kr,
    const u16* __restrict__ Vt, u16* __restrict__ Oc,
    float* __restrict__ PO, float* __restrict__ PML) {
  __shared__ u16 Kl[2][4096];   // [buf][64 keys x 64 d], granule-swizzled
  __shared__ u16 Vl[2][4096];   // [buf][64 d x 64 keys], granule-swizzled

  const int x = blockIdx.x;          // 0..511
  const int bh = x & 31;             // XCD = x%8 = bh%8 -> 4 heads per XCD L2
  const int slot = x >> 5;           // 0..15
  const int p = slot & 7;
  const int half = slot >> 3;
  const int iH = 15 - p, iL = p;
  const int nH = 2 * iH + 2;
  const int b = bh >> 4, h = bh & 15;
  const int tid = threadIdx.x;
  const int w = tid >> 6;
  const int lane = tid & 63;
  const int g = lane >> 4, cc = lane & 15;

  const u16* Kp = Kr + (size_t)bh * (Sdim * 64);
  const u16* Vp = Vt + (size_t)bh * (64 * Sdim);

  // staging sources (pre-swizzled, T21): granule ^= row_local&7
  const int rloc = lane >> 3;
  const int sg = (lane & 7) ^ rloc;
  const u16* kS = Kp + (size_t)(w * 16 + rloc) * 64 + sg * 8;
  const u16* vS = Vp + (size_t)(w * 16 + rloc) * 2048 + sg * 8;

  auto stageKV = [&](int t, int buf) {
    const size_t ko = (size_t)t * 4096;
    const size_t vo = (size_t)t * 64;
    gload_lds16(kS + ko, &Kl[buf][w * 1024]);
    gload_lds16(kS + ko + 512, &Kl[buf][w * 1024 + 512]);
    gload_lds16(vS + vo, &Vl[buf][w * 1024]);
    gload_lds16(vS + vo + 16384, &Vl[buf][w * 1024 + 512]);
  };

  auto runseg = [&](int tile, int c0, int c1, int part) {
    const int myDiag = 2 * tile + (w >> 1);
    const u16* Qp = Qr + (size_t)(bh * Sdim + tile * 128 + w * 32) * 64;
    bf16x8 qf[4];
    qf[0] = *(const bf16x8*)(Qp + cc * 64 + g * 8);
    qf[1] = *(const bf16x8*)(Qp + cc * 64 + g * 8 + 32);
    qf[2] = *(const bf16x8*)(Qp + (16 + cc) * 64 + g * 8);
    qf[3] = *(const bf16x8*)(Qp + (16 + cc) * 64 + g * 8 + 32);

    float mold0 = -1e30f, mold1 = -1e30f, lsum0 = 0.f, lsum1 = 0.f;
    f32x4 ot0[4] = {}, ot1[4] = {};

    __syncthreads();                 // LDS safe to overwrite (prev segment done)
    stageKV(c0, c0 & 1);
    for (int t = c0; t < c1; ++t) {
      __syncthreads();               // drains stage(t)
      if (t + 1 < c1) stageKV(t + 1, (t + 1) & 1);
      if (t <= myDiag) {
        const u16* kl = &Kl[t & 1][0];
        const u16* vl = &Vl[t & 1][0];
        if (t < myDiag)
          attn_chunk64<0, 0>(kl, vl, cc, g, qf, mold0, mold1, lsum0, lsum1, ot0, ot1);
        else if (w & 1)
          attn_chunk64<0, 1>(kl, vl, cc, g, qf, mold0, mold1, lsum0, lsum1, ot0, ot1);
        else
          attn_chunk64<1, 2>(kl, vl, cc, g, qf, mold0, mold1, lsum0, lsum1, ot0, ot1);
      }
    }

    float l0 = lsum0 + __shfl_xor(lsum0, 16);
    l0 += __shfl_xor(l0, 32);
    float l1 = lsum1 + __shfl_xor(lsum1, 16);
    l1 += __shfl_xor(l1, 32);

    if (part < 0) {
      const float rl0 = 1.0f / l0, rl1 = 1.0f / l1;
      u16* dst0 = Oc + (size_t)(b * Sdim + tile * 128 + w * 32 + cc) * Ddim + h * 64 + g * 4;
      u16* dst1 = dst0 + 16 * Ddim;
#pragma unroll
      for (int dc = 0; dc < 4; ++dc) {
        ushort4 o0, o1;
        o0.x = f2b(ot0[dc][0] * rl0);
        o0.y = f2b(ot0[dc][1] * rl0);
        o0.z = f2b(ot0[dc][2] * rl0);
        o0.w = f2b(ot0[dc][3] * rl0);
        o1.x = f2b(ot1[dc][0] * rl1);
        o1.y = f2b(ot1[dc][1] * rl1);
        o1.z = f2b(ot1[dc][2] * rl1);
        o1.w = f2b(ot1[dc][3] * rl1);
        *(ushort4*)(dst0 + dc * 16) = o0;
        *(ushort4*)(dst1 + dc * 16) = o1;
      }
    } else {
      const int slotp = (bh * 7 + p) * 2 + part;
      float* po0 = PO + (size_t)slotp * 8192 + (w * 32 + cc) * 64;
      float* po1 = po0 + 16 * 64;
#pragma unroll
      for (int dc = 0; dc < 4; ++dc) {
        *(f32x4*)(po0 + dc * 16 + g * 4) = ot0[dc];
        *(f32x4*)(po1 + dc * 16 + g * 4) = ot1[dc];
      }
      if (g == 0) {
        float* ml = PML + (size_t)slotp * 256 + (w * 32 + cc) * 2;
        ml[0] = mold0;
        ml[1] = l0;
        ml[32] = mold1;
        ml[33] = l1;
      }
    }
  };

  if (half == 0) {
    runseg(iH, 0, (nH < 18) ? nH : 18, (nH > 18) ? 0 : -1);
  } else {
    if (p < 7) runseg(iH, 18, nH, 1);
    runseg(iL, 0, 2 * iL + 2, -1);
  }
}

// ---------------------------------------------------------------------------
// Kernel 7: combine split-K partials for heavy tiles (iH = 9..15).
// ---------------------------------------------------------------------------
__global__ __launch_bounds__(128) void k_comb(
    const float* __restrict__ PO, const float* __restrict__ PML,
    u16* __restrict__ Oc) {
  const int x = blockIdx.x;          // 0..223 = bh*7 + p
  const int bh = x / 7, p = x % 7;
  const int b = bh >> 4, h = bh & 15;
  const int iH = 15 - p;
  const int row = threadIdx.x;       // 0..127
  const float* ml0 = PML + (size_t)(x * 2 + 0) * 256 + row * 2;
  const float* ml1 = PML + (size_t)(x * 2 + 1) * 256 + row * 2;
  const float m0 = ml0[0], l0 = ml0[1];
  const float m1 = ml1[0], l1 = ml1[1];
  const float M = fmaxf(m0, m1);
  float e0 = exp2f(m0 - M), e1 = exp2f(m1 - M);
  const float inv = 1.0f / (e0 * l0 + e1 * l1);
  e0 *= inv; e1 *= inv;
  const float* O0 = PO + (size_t)(x * 2 + 0) * 8192 + row * 64;
  const float* O1 = PO + (size_t)(x * 2 + 1) * 8192 + row * 64;
  u16* dst = Oc + (size_t)(b * Sdim + iH * 128 + row) * Ddim + h * 64;
#pragma unroll
  for (int c = 0; c < 64; c += 4) {
    float4 a = *(const float4*)(O0 + c);
    float4 bb = *(const float4*)(O1 + c);
    ushort4 o;
    o.x = f2b(a.x * e0 + bb.x * e1);
    o.y = f2b(a.y * e0 + bb.y * e1);
    o.z = f2b(a.z * e0 + bb.z * e1);
    o.w = f2b(a.w * e0 + bb.w * e1);
    *(ushort4*)(dst + c) = o;
  }
}

// ---------------------------------------------------------------------------
extern "C" void kernel_launch(void* const* d_in, const int* in_sizes, int n_in,
                              void* d_out, int out_size, void* d_ws, size_t ws_size,
                              hipStream_t stream) {
  const float* q = (const float*)d_in[0];
  const float* k = (const float*)d_in[1];
  const float* v = (const float*)d_in[2];
  const float* wq = (const float*)d_in[3];
  const float* wk = (const float*)d_in[4];
  const float* wv = (const float*)d_in[5];
  const float* wo = (const float*)d_in[6];
  float* out = (float*)d_out;

  uint8_t* ws = (uint8_t*)d_ws;
  const size_t MiB = 1ull << 20;
  u16* qb  = (u16*)(ws + 0 * MiB);
  u16* kb  = (u16*)(ws + 8 * MiB);
  u16* vb  = (u16*)(ws + 16 * MiB);
  u16* wqb = (u16*)(ws + 24 * MiB);
  u16* wkb = (u16*)(ws + 26 * MiB);
  u16* wvb = (u16*)(ws + 28 * MiB);
  u16* wob = (u16*)(ws + 30 * MiB);
  u16* tQ  = (u16*)(ws + 32 * MiB);
  u16* tK  = (u16*)(ws + 40 * MiB);
  u16* tV  = (u16*)(ws + 48 * MiB);
  u16* Qr  = (u16*)(ws + 56 * MiB);
  u16* Kr  = (u16*)(ws + 64 * MiB);
  u16* Vt  = (u16*)(ws + 72 * MiB);
  u16* Oc  = (u16*)(ws + 80 * MiB);
  float* cosT = (float*)(ws + 88 * MiB);
  float* sinT = (float*)(ws + 88 * MiB + 256 * 1024);
  // split-K partials: reuse qb/kb region (dead after k_gemm<0>/k_rope)
  float* PO  = (float*)(ws + 0 * MiB);            // 224*2*8192*4 = 14.68 MB
  float* PML = (float*)(ws + 15 * MiB);           // 224*2*256*4  = 458 KB

  k_convert<<<16384, 256, 0, stream>>>(q, k, v, wq, wk, wv, wo,
                                       qb, kb, vb, wqb, wkb, wvb, wob);
  k_ropetab<<<256, 256, 0, stream>>>(cosT, sinT);
  k_gemm<0><<<dim3(32, 8, 3), 256, 0, stream>>>(qb, wqb, tQ, kb, wkb, tK, vb, wvb, tV);
  k_rope<<<16384, 256, 0, stream>>>(tQ, tK, cosT, sinT, Qr, Kr);
  k_transv<<<dim3(32, 32), 256, 0, stream>>>(tV, Vt);
  k_attn<<<512, 256, 0, stream>>>(Qr, Kr, Vt, Oc, PO, PML);
  k_comb<<<224, 128, 0, stream>>>(PO, PML, Oc);
  k_gemm<1><<<dim3(32, 8, 1), 256, 0, stream>>>(Oc, wob, out, Oc, wob, out, Oc, wob, out);
}